// Round 1
// baseline (2021.603 us; speedup 1.0000x reference)
//
#include <hip/hip_runtime.h>

namespace {

constexpr int kUsers = 100000;
constexpr int kItems = 200000;
constexpr int kN     = kUsers + kItems;   // 300000
constexpr int kD     = 64;
constexpr int kNNZ   = 5000000;
constexpr int kB     = 16384;
constexpr int kChunk = 2048;                            // elems per scan block (256 thr x 8)
constexpr int kNB    = (kN + kChunk - 1) / kChunk;      // 147 scan blocks

__global__ void zero_i32(int* __restrict__ p, int n) {
  int i = blockIdx.x * blockDim.x + threadIdx.x;
  if (i < n) p[i] = 0;
}

__global__ void hist_rows(const int* __restrict__ row, int* __restrict__ counts) {
  int i = blockIdx.x * blockDim.x + threadIdx.x;
  if (i < kNNZ) atomicAdd(&counts[row[i]], 1);
}

// Block-local exclusive scan of counts -> rowptr (chunk-local), chunk totals -> partials.
__global__ void scan1(const int* __restrict__ counts, int* __restrict__ rowptr,
                      int* __restrict__ partials) {
  __shared__ int lds[256];
  int t = threadIdx.x;
  int base = blockIdx.x * kChunk + t * 8;
  int pref[8];
  int s = 0;
#pragma unroll
  for (int j = 0; j < 8; ++j) {
    int idx = base + j;
    int c = (idx < kN) ? counts[idx] : 0;
    pref[j] = s;
    s += c;
  }
  lds[t] = s;
  __syncthreads();
  for (int o = 1; o < 256; o <<= 1) {
    int v = 0;
    if (t >= o) v = lds[t - o];
    __syncthreads();
    if (t >= o) lds[t] += v;
    __syncthreads();
  }
  int excl = (t == 0) ? 0 : lds[t - 1];
  if (t == 255) partials[blockIdx.x] = lds[255];
#pragma unroll
  for (int j = 0; j < 8; ++j) {
    int idx = base + j;
    if (idx < kN) rowptr[idx] = excl + pref[j];
  }
}

// Exclusive scan of the (<=256) chunk totals, in place.
__global__ void scan2(int* __restrict__ partials) {
  __shared__ int lds[256];
  int t = threadIdx.x;
  lds[t] = (t < kNB) ? partials[t] : 0;
  __syncthreads();
  for (int o = 1; o < 256; o <<= 1) {
    int v = 0;
    if (t >= o) v = lds[t - o];
    __syncthreads();
    if (t >= o) lds[t] += v;
    __syncthreads();
  }
  int excl = (t == 0) ? 0 : lds[t - 1];
  if (t < kNB) partials[t] = excl;
}

// Add chunk offsets -> final rowptr; copy into write-position array; rowptr[N] = NNZ.
__global__ void scan3(int* __restrict__ rowptr, const int* __restrict__ partials,
                      int* __restrict__ wpos) {
  int i = blockIdx.x * blockDim.x + threadIdx.x;
  if (i < kN) {
    int v = rowptr[i] + partials[i >> 11];
    rowptr[i] = v;
    wpos[i] = v;
  } else if (i == kN) {
    rowptr[kN] = kNNZ;
  }
}

__global__ void scatter_edges(const int* __restrict__ row, const int* __restrict__ col,
                              const float* __restrict__ val, int* __restrict__ wpos,
                              int* __restrict__ ccol, float* __restrict__ cval) {
  int i = blockIdx.x * blockDim.x + threadIdx.x;
  if (i >= kNNZ) return;
  int r = row[i];
  int p = atomicAdd(&wpos[r], 1);
  ccol[p] = col[i];
  cval[p] = val[i];
}

// One wave (64 lanes) per row; lane d owns dim d. Gather-sum, no atomics.
// FIRST layer reads the virtual concat(user_emb, item_emb) instead of x.
template <bool FIRST>
__global__ void spmm(const int* __restrict__ rowptr, const int* __restrict__ ccol,
                     const float* __restrict__ cval, const float* __restrict__ x,
                     const float* __restrict__ uemb, const float* __restrict__ iemb,
                     float* __restrict__ y) {
  int wave = threadIdx.x >> 6;
  int d = threadIdx.x & 63;
  int r = blockIdx.x * 4 + wave;
  if (r >= kN) return;
  int s = rowptr[r], e = rowptr[r + 1];
  float sum = 0.f;
  for (int j = s; j < e; ++j) {
    int c = ccol[j];
    float v = cval[j];
    const float* src;
    if (FIRST)
      src = (c < kUsers) ? (uemb + (size_t)c * kD) : (iemb + (size_t)(c - kUsers) * kD);
    else
      src = x + (size_t)c * kD;
    sum += v * src[d];
  }
  y[(size_t)r * kD + d] = sum;
}

__global__ void acc_init(const int* __restrict__ users, const int* __restrict__ items,
                         const float* __restrict__ uemb, const float* __restrict__ iemb,
                         float* __restrict__ uacc, float* __restrict__ iacc) {
  int tid = blockIdx.x * blockDim.x + threadIdx.x;
  if (tid >= kB * kD) return;
  int b = tid >> 6, d = tid & 63;
  uacc[tid] = uemb[(size_t)users[b] * kD + d];
  iacc[tid] = iemb[(size_t)items[b] * kD + d];
}

__global__ void acc_add(const int* __restrict__ users, const int* __restrict__ items,
                        const float* __restrict__ x, float* __restrict__ uacc,
                        float* __restrict__ iacc) {
  int tid = blockIdx.x * blockDim.x + threadIdx.x;
  if (tid >= kB * kD) return;
  int b = tid >> 6, d = tid & 63;
  uacc[tid] += x[(size_t)users[b] * kD + d];
  iacc[tid] += x[(size_t)(kUsers + items[b]) * kD + d];
}

// gamma[b] = dot(acc_u, acc_i) / (n_layers+1)^2 = dot / 16
__global__ void finalize(const float* __restrict__ uacc, const float* __restrict__ iacc,
                         float* __restrict__ out) {
  int tid = blockIdx.x * blockDim.x + threadIdx.x;
  if (tid >= kB * kD) return;
  int b = tid >> 6, d = tid & 63;
  float p = uacc[tid] * iacc[tid];
  for (int o = 32; o > 0; o >>= 1) p += __shfl_down(p, o, 64);
  if (d == 0) out[b] = p * 0.0625f;
}

}  // namespace

extern "C" void kernel_launch(void* const* d_in, const int* in_sizes, int n_in,
                              void* d_out, int out_size, void* d_ws, size_t ws_size,
                              hipStream_t stream) {
  const int*   users = (const int*)d_in[0];
  const int*   items = (const int*)d_in[1];
  const int*   erow  = (const int*)d_in[2];
  const int*   ecol  = (const int*)d_in[3];
  const float* evals = (const float*)d_in[4];
  const float* uemb  = (const float*)d_in[5];
  const float* iemb  = (const float*)d_in[6];
  float* out = (float*)d_out;

  char* ws = (char*)d_ws;
  size_t off = 0;
  auto take = [&](size_t bytes) -> char* {
    char* p = ws + off;
    off = (off + bytes + 255) & ~(size_t)255;
    return p;
  };
  int*   counts   = (int*)take((size_t)kN * 4);          // reused as write positions
  int*   rowptr   = (int*)take((size_t)(kN + 1) * 4);
  int*   partials = (int*)take(256 * 4);
  int*   ccol     = (int*)take((size_t)kNNZ * 4);
  float* cval     = (float*)take((size_t)kNNZ * 4);
  float* xA       = (float*)take((size_t)kN * kD * 4);
  float* xB       = (float*)take((size_t)kN * kD * 4);
  float* uacc     = (float*)take((size_t)kB * kD * 4);
  float* iacc     = (float*)take((size_t)kB * kD * 4);
  (void)ws_size; (void)in_sizes; (void)n_in; (void)out_size;

  // --- CSR build (once per launch; ws is re-poisoned every call) ---
  zero_i32<<<(kN + 255) / 256, 256, 0, stream>>>(counts, kN);
  hist_rows<<<(kNNZ + 255) / 256, 256, 0, stream>>>(erow, counts);
  scan1<<<kNB, 256, 0, stream>>>(counts, rowptr, partials);
  scan2<<<1, 256, 0, stream>>>(partials);
  scan3<<<(kN + 1 + 255) / 256, 256, 0, stream>>>(rowptr, partials, counts);
  scatter_edges<<<(kNNZ + 255) / 256, 256, 0, stream>>>(erow, ecol, evals, counts, ccol, cval);

  // --- acc = all_emb term for the selected pairs ---
  acc_init<<<(kB * kD) / 256, 256, 0, stream>>>(users, items, uemb, iemb, uacc, iacc);

  // --- 3 propagation layers, ping-pong xA/xB ---
  spmm<true ><<<kN / 4, 256, 0, stream>>>(rowptr, ccol, cval, nullptr, uemb, iemb, xA);
  acc_add<<<(kB * kD) / 256, 256, 0, stream>>>(users, items, xA, uacc, iacc);
  spmm<false><<<kN / 4, 256, 0, stream>>>(rowptr, ccol, cval, xA, uemb, iemb, xB);
  acc_add<<<(kB * kD) / 256, 256, 0, stream>>>(users, items, xB, uacc, iacc);
  spmm<false><<<kN / 4, 256, 0, stream>>>(rowptr, ccol, cval, xB, uemb, iemb, xA);
  acc_add<<<(kB * kD) / 256, 256, 0, stream>>>(users, items, xA, uacc, iacc);

  finalize<<<(kB * kD) / 256, 256, 0, stream>>>(uacc, iacc, out);
}

// Round 2
// 1296.774 us; speedup vs baseline: 1.5589x; 1.5589x over previous
//
#include <hip/hip_runtime.h>

namespace {

constexpr int kUsers = 100000;
constexpr int kItems = 200000;
constexpr int kN     = kUsers + kItems;   // 300000
constexpr int kD     = 64;
constexpr int kNNZ   = 5000000;
constexpr int kB     = 16384;
constexpr int kChunk = 2048;                            // elems per scan block (256 thr x 8)
constexpr int kNB    = (kN + kChunk - 1) / kChunk;      // 147 scan blocks

__global__ void zero_i32(int* __restrict__ p, int n) {
  int i = blockIdx.x * blockDim.x + threadIdx.x;
  if (i < n) p[i] = 0;
}

__global__ void hist_rows(const int* __restrict__ row, int* __restrict__ counts) {
  int i = blockIdx.x * blockDim.x + threadIdx.x;
  if (i < kNNZ) atomicAdd(&counts[row[i]], 1);
}

// Block-local exclusive scan of counts -> rowptr (chunk-local), chunk totals -> partials.
__global__ void scan1(const int* __restrict__ counts, int* __restrict__ rowptr,
                      int* __restrict__ partials) {
  __shared__ int lds[256];
  int t = threadIdx.x;
  int base = blockIdx.x * kChunk + t * 8;
  int pref[8];
  int s = 0;
#pragma unroll
  for (int j = 0; j < 8; ++j) {
    int idx = base + j;
    int c = (idx < kN) ? counts[idx] : 0;
    pref[j] = s;
    s += c;
  }
  lds[t] = s;
  __syncthreads();
  for (int o = 1; o < 256; o <<= 1) {
    int v = 0;
    if (t >= o) v = lds[t - o];
    __syncthreads();
    if (t >= o) lds[t] += v;
    __syncthreads();
  }
  int excl = (t == 0) ? 0 : lds[t - 1];
  if (t == 255) partials[blockIdx.x] = lds[255];
#pragma unroll
  for (int j = 0; j < 8; ++j) {
    int idx = base + j;
    if (idx < kN) rowptr[idx] = excl + pref[j];
  }
}

// Exclusive scan of the (<=256) chunk totals, in place.
__global__ void scan2(int* __restrict__ partials) {
  __shared__ int lds[256];
  int t = threadIdx.x;
  lds[t] = (t < kNB) ? partials[t] : 0;
  __syncthreads();
  for (int o = 1; o < 256; o <<= 1) {
    int v = 0;
    if (t >= o) v = lds[t - o];
    __syncthreads();
    if (t >= o) lds[t] += v;
    __syncthreads();
  }
  int excl = (t == 0) ? 0 : lds[t - 1];
  if (t < kNB) partials[t] = excl;
}

// Add chunk offsets -> final rowptr; copy into write-position array; rowptr[N] = NNZ.
__global__ void scan3(int* __restrict__ rowptr, const int* __restrict__ partials,
                      int* __restrict__ wpos) {
  int i = blockIdx.x * blockDim.x + threadIdx.x;
  if (i < kN) {
    int v = rowptr[i] + partials[i >> 11];
    rowptr[i] = v;
    wpos[i] = v;
  } else if (i == kN) {
    rowptr[kN] = kNNZ;
  }
}

// Packed edge: .x = col, .y = val bits. One 8B random write per edge.
__global__ void scatter_edges(const int* __restrict__ row, const int* __restrict__ col,
                              const float* __restrict__ val, int* __restrict__ wpos,
                              int2* __restrict__ edges) {
  int i = blockIdx.x * blockDim.x + threadIdx.x;
  if (i >= kNNZ) return;
  int r = row[i];
  int p = atomicAdd(&wpos[r], 1);
  edges[p] = make_int2(col[i], __float_as_int(val[i]));
}

// One wave per row. Lane layout: eslot = lane>>4 (4 edge slots), l16 = lane&15
// (dims l16*4..+3 via float4). Each loop iteration keeps 4 independent 256B
// row-gathers in flight (4x MLP vs scalar-dim version). Cross-slot reduce by
// __shfl_xor 16/32.
template <bool FIRST>
__global__ void spmm(const int* __restrict__ rowptr, const int2* __restrict__ edges,
                     const float* __restrict__ x, const float* __restrict__ uemb,
                     const float* __restrict__ iemb, float* __restrict__ y) {
  int wave = threadIdx.x >> 6;
  int lane = threadIdx.x & 63;
  int eslot = lane >> 4;
  int l16 = lane & 15;
  int r = blockIdx.x * 4 + wave;
  if (r >= kN) return;
  int s = rowptr[r], e = rowptr[r + 1];
  float4 sum = make_float4(0.f, 0.f, 0.f, 0.f);
  for (int j = s + eslot; j < e; j += 4) {
    int2 epk = edges[j];                 // broadcast within 16-lane group
    int c = epk.x;
    float v = __int_as_float(epk.y);
    const float* src;
    if (FIRST)
      src = (c < kUsers) ? (uemb + (size_t)c * kD) : (iemb + (size_t)(c - kUsers) * kD);
    else
      src = x + (size_t)c * kD;
    float4 xv = ((const float4*)src)[l16];
    sum.x += v * xv.x;
    sum.y += v * xv.y;
    sum.z += v * xv.z;
    sum.w += v * xv.w;
  }
#pragma unroll
  for (int m = 16; m <= 32; m <<= 1) {
    sum.x += __shfl_xor(sum.x, m, 64);
    sum.y += __shfl_xor(sum.y, m, 64);
    sum.z += __shfl_xor(sum.z, m, 64);
    sum.w += __shfl_xor(sum.w, m, 64);
  }
  if (eslot == 0) ((float4*)y)[(size_t)r * 16 + l16] = sum;
}

__global__ void acc_init(const int* __restrict__ users, const int* __restrict__ items,
                         const float* __restrict__ uemb, const float* __restrict__ iemb,
                         float* __restrict__ uacc, float* __restrict__ iacc) {
  int tid = blockIdx.x * blockDim.x + threadIdx.x;
  if (tid >= kB * kD) return;
  int b = tid >> 6, d = tid & 63;
  uacc[tid] = uemb[(size_t)users[b] * kD + d];
  iacc[tid] = iemb[(size_t)items[b] * kD + d];
}

__global__ void acc_add(const int* __restrict__ users, const int* __restrict__ items,
                        const float* __restrict__ x, float* __restrict__ uacc,
                        float* __restrict__ iacc) {
  int tid = blockIdx.x * blockDim.x + threadIdx.x;
  if (tid >= kB * kD) return;
  int b = tid >> 6, d = tid & 63;
  uacc[tid] += x[(size_t)users[b] * kD + d];
  iacc[tid] += x[(size_t)(kUsers + items[b]) * kD + d];
}

// gamma[b] = dot(acc_u, acc_i) / (n_layers+1)^2 = dot / 16
__global__ void finalize(const float* __restrict__ uacc, const float* __restrict__ iacc,
                         float* __restrict__ out) {
  int tid = blockIdx.x * blockDim.x + threadIdx.x;
  if (tid >= kB * kD) return;
  int b = tid >> 6, d = tid & 63;
  float p = uacc[tid] * iacc[tid];
  for (int o = 32; o > 0; o >>= 1) p += __shfl_down(p, o, 64);
  if (d == 0) out[b] = p * 0.0625f;
}

}  // namespace

extern "C" void kernel_launch(void* const* d_in, const int* in_sizes, int n_in,
                              void* d_out, int out_size, void* d_ws, size_t ws_size,
                              hipStream_t stream) {
  const int*   users = (const int*)d_in[0];
  const int*   items = (const int*)d_in[1];
  const int*   erow  = (const int*)d_in[2];
  const int*   ecol  = (const int*)d_in[3];
  const float* evals = (const float*)d_in[4];
  const float* uemb  = (const float*)d_in[5];
  const float* iemb  = (const float*)d_in[6];
  float* out = (float*)d_out;

  char* ws = (char*)d_ws;
  size_t off = 0;
  auto take = [&](size_t bytes) -> char* {
    char* p = ws + off;
    off = (off + bytes + 255) & ~(size_t)255;
    return p;
  };
  int*   counts   = (int*)take((size_t)kN * 4);          // reused as write positions
  int*   rowptr   = (int*)take((size_t)(kN + 1) * 4);
  int*   partials = (int*)take(256 * 4);
  int2*  edges    = (int2*)take((size_t)kNNZ * 8);
  float* xA       = (float*)take((size_t)kN * kD * 4);
  float* xB       = (float*)take((size_t)kN * kD * 4);
  float* uacc     = (float*)take((size_t)kB * kD * 4);
  float* iacc     = (float*)take((size_t)kB * kD * 4);
  (void)ws_size; (void)in_sizes; (void)n_in; (void)out_size;

  // --- CSR build (once per launch; ws is re-poisoned every call) ---
  zero_i32<<<(kN + 255) / 256, 256, 0, stream>>>(counts, kN);
  hist_rows<<<(kNNZ + 255) / 256, 256, 0, stream>>>(erow, counts);
  scan1<<<kNB, 256, 0, stream>>>(counts, rowptr, partials);
  scan2<<<1, 256, 0, stream>>>(partials);
  scan3<<<(kN + 1 + 255) / 256, 256, 0, stream>>>(rowptr, partials, counts);
  scatter_edges<<<(kNNZ + 255) / 256, 256, 0, stream>>>(erow, ecol, evals, counts, edges);

  // --- acc = all_emb term for the selected pairs ---
  acc_init<<<(kB * kD) / 256, 256, 0, stream>>>(users, items, uemb, iemb, uacc, iacc);

  // --- 3 propagation layers, ping-pong xA/xB ---
  spmm<true ><<<kN / 4, 256, 0, stream>>>(rowptr, edges, nullptr, uemb, iemb, xA);
  acc_add<<<(kB * kD) / 256, 256, 0, stream>>>(users, items, xA, uacc, iacc);
  spmm<false><<<kN / 4, 256, 0, stream>>>(rowptr, edges, xA, uemb, iemb, xB);
  acc_add<<<(kB * kD) / 256, 256, 0, stream>>>(users, items, xB, uacc, iacc);
  spmm<false><<<kN / 4, 256, 0, stream>>>(rowptr, edges, xB, uemb, iemb, xA);
  acc_add<<<(kB * kD) / 256, 256, 0, stream>>>(users, items, xA, uacc, iacc);

  finalize<<<(kB * kD) / 256, 256, 0, stream>>>(uacc, iacc, out);
}

// Round 3
// 983.183 us; speedup vs baseline: 2.0562x; 1.3190x over previous
//
#include <hip/hip_runtime.h>

namespace {

constexpr int kUsers = 100000;
constexpr int kItems = 200000;
constexpr int kN     = kUsers + kItems;   // 300000
constexpr int kD     = 64;
constexpr int kNNZ   = 5000000;
constexpr int kB     = 16384;
constexpr int kRowsPerBkt = 2048;                       // rows per coarse bucket
constexpr int kNBKT  = (kN + kRowsPerBkt - 1) / kRowsPerBkt;  // 147
constexpr int kEPB   = 2048;                            // edges per scatter block

__global__ void zero_i32(int* __restrict__ p, int n) {
  int i = blockIdx.x * blockDim.x + threadIdx.x;
  if (i < n) p[i] = 0;
}

// Per-block LDS histogram of coarse buckets, flushed with one atomic per bucket.
__global__ void bin_count(const int* __restrict__ row, int* __restrict__ bcnt) {
  __shared__ int h[kNBKT];
  int t = threadIdx.x;
  for (int i = t; i < kNBKT; i += 256) h[i] = 0;
  __syncthreads();
  long base = (long)blockIdx.x * kEPB + t;
#pragma unroll
  for (int j = 0; j < 8; ++j) {
    long i = base + j * 256;
    if (i < kNNZ) atomicAdd(&h[row[i] >> 11], 1);
  }
  __syncthreads();
  for (int i = t; i < kNBKT; i += 256)
    if (h[i]) atomicAdd(&bcnt[i], h[i]);
}

// Exclusive scan of 147 bucket counts; bbase[kNBKT] = total; gpos = running cursors.
__global__ void bucket_scan(const int* __restrict__ bcnt, int* __restrict__ bbase,
                            int* __restrict__ gpos) {
  __shared__ int lds[256];
  int t = threadIdx.x;
  lds[t] = (t < kNBKT) ? bcnt[t] : 0;
  __syncthreads();
  for (int o = 1; o < 256; o <<= 1) {
    int v = (t >= o) ? lds[t - o] : 0;
    __syncthreads();
    if (t >= o) lds[t] += v;
    __syncthreads();
  }
  int ex = (t == 0) ? 0 : lds[t - 1];
  if (t < kNBKT) { bbase[t] = ex; gpos[t] = ex; }
  if (t == kNBKT) bbase[t] = ex;   // == kNNZ
}

// Bin 2048 edges into coarse buckets: local LDS ranks + per-bucket global
// reservation -> block-contiguous runs (~14 edges each) in tmp. Packed edge:
// .x = (rowlocal<<19)|col  (11b + 19b = 30b), .y = val bits.
__global__ void bucket_scatter(const int* __restrict__ row, const int* __restrict__ col,
                               const float* __restrict__ val, int* __restrict__ gpos,
                               int2* __restrict__ tmp) {
  __shared__ int hcnt[kNBKT];
  __shared__ int hbase[kNBKT];
  int t = threadIdx.x;
  long base = (long)blockIdx.x * kEPB;
  for (int i = t; i < kNBKT; i += 256) hcnt[i] = 0;
  __syncthreads();
  int pk[8], bk[8], rk[8];
  float v[8];
  bool ok[8];
#pragma unroll
  for (int j = 0; j < 8; ++j) {
    long i = base + j * 256 + t;
    ok[j] = (i < kNNZ);
    if (ok[j]) {
      int r = row[i];
      bk[j] = r >> 11;
      pk[j] = ((r & 2047) << 19) | col[i];
      v[j] = val[i];
      rk[j] = atomicAdd(&hcnt[bk[j]], 1);
    }
  }
  __syncthreads();
  for (int i = t; i < kNBKT; i += 256) hbase[i] = atomicAdd(&gpos[i], hcnt[i]);
  __syncthreads();
#pragma unroll
  for (int j = 0; j < 8; ++j)
    if (ok[j]) tmp[hbase[bk[j]] + rk[j]] = make_int2(pk[j], __float_as_int(v[j]));
}

// One WG per bucket: local row-hist + scan (produces rowptr), then scatter to
// final CSR slots — random writes confined to this bucket's ~272 KB window
// (single-WG-owned -> L2-resident, written back once).
__global__ void bucket_finalize(const int* __restrict__ bbase, const int2* __restrict__ tmp,
                                int* __restrict__ rowptr, int2* __restrict__ edges) {
  __shared__ int lcnt[kRowsPerBkt];
  __shared__ int lexcl[kRowsPerBkt];
  __shared__ int lsum[256];
  int b = blockIdx.x;
  int t = threadIdx.x;
  int base = bbase[b], end = bbase[b + 1];
  int cnt = end - base;
  for (int r = t; r < kRowsPerBkt; r += 256) lcnt[r] = 0;
  __syncthreads();
  for (int j = t; j < cnt; j += 256)
    atomicAdd(&lcnt[tmp[base + j].x >> 19], 1);
  __syncthreads();
  int s = 0, pref[8];
#pragma unroll
  for (int k = 0; k < 8; ++k) { pref[k] = s; s += lcnt[t * 8 + k]; }
  lsum[t] = s;
  __syncthreads();
  for (int o = 1; o < 256; o <<= 1) {
    int v = (t >= o) ? lsum[t - o] : 0;
    __syncthreads();
    if (t >= o) lsum[t] += v;
    __syncthreads();
  }
  int ex = (t == 0) ? 0 : lsum[t - 1];
#pragma unroll
  for (int k = 0; k < 8; ++k) lexcl[t * 8 + k] = ex + pref[k];
  __syncthreads();
  for (int r = t; r < kRowsPerBkt; r += 256) {
    int gr = b * kRowsPerBkt + r;
    if (gr < kN) rowptr[gr] = base + lexcl[r];
    lcnt[r] = 0;   // reuse as placement cursor
  }
  if (b == 0 && t == 0) rowptr[kN] = kNNZ;
  __syncthreads();
  for (int j = t; j < cnt; j += 256) {
    int2 e = tmp[base + j];
    int rl = e.x >> 19;
    int rk = atomicAdd(&lcnt[rl], 1);
    edges[base + lexcl[rl] + rk] = make_int2(e.x & 0x7FFFF, e.y);
  }
}

// One wave per row. 4 edge slots x 16 dim-lanes (float4) -> 4 independent
// 256B row-gathers in flight per iteration. Cross-slot reduce via shfl_xor.
template <bool FIRST>
__global__ void spmm(const int* __restrict__ rowptr, const int2* __restrict__ edges,
                     const float* __restrict__ x, const float* __restrict__ uemb,
                     const float* __restrict__ iemb, float* __restrict__ y) {
  int wave = threadIdx.x >> 6;
  int lane = threadIdx.x & 63;
  int eslot = lane >> 4;
  int l16 = lane & 15;
  int r = blockIdx.x * 4 + wave;
  if (r >= kN) return;
  int s = rowptr[r], e = rowptr[r + 1];
  float4 sum = make_float4(0.f, 0.f, 0.f, 0.f);
  for (int j = s + eslot; j < e; j += 4) {
    int2 epk = edges[j];
    int c = epk.x;
    float v = __int_as_float(epk.y);
    const float* src;
    if (FIRST)
      src = (c < kUsers) ? (uemb + (size_t)c * kD) : (iemb + (size_t)(c - kUsers) * kD);
    else
      src = x + (size_t)c * kD;
    float4 xv = ((const float4*)src)[l16];
    sum.x += v * xv.x;
    sum.y += v * xv.y;
    sum.z += v * xv.z;
    sum.w += v * xv.w;
  }
#pragma unroll
  for (int m = 16; m <= 32; m <<= 1) {
    sum.x += __shfl_xor(sum.x, m, 64);
    sum.y += __shfl_xor(sum.y, m, 64);
    sum.z += __shfl_xor(sum.z, m, 64);
    sum.w += __shfl_xor(sum.w, m, 64);
  }
  if (eslot == 0) ((float4*)y)[(size_t)r * 16 + l16] = sum;
}

__global__ void acc_init(const int* __restrict__ users, const int* __restrict__ items,
                         const float* __restrict__ uemb, const float* __restrict__ iemb,
                         float* __restrict__ uacc, float* __restrict__ iacc) {
  int tid = blockIdx.x * blockDim.x + threadIdx.x;
  if (tid >= kB * kD) return;
  int b = tid >> 6, d = tid & 63;
  uacc[tid] = uemb[(size_t)users[b] * kD + d];
  iacc[tid] = iemb[(size_t)items[b] * kD + d];
}

__global__ void acc_add(const int* __restrict__ users, const int* __restrict__ items,
                        const float* __restrict__ x, float* __restrict__ uacc,
                        float* __restrict__ iacc) {
  int tid = blockIdx.x * blockDim.x + threadIdx.x;
  if (tid >= kB * kD) return;
  int b = tid >> 6, d = tid & 63;
  uacc[tid] += x[(size_t)users[b] * kD + d];
  iacc[tid] += x[(size_t)(kUsers + items[b]) * kD + d];
}

// gamma[b] = dot(acc_u, acc_i) / 16
__global__ void finalize(const float* __restrict__ uacc, const float* __restrict__ iacc,
                         float* __restrict__ out) {
  int tid = blockIdx.x * blockDim.x + threadIdx.x;
  if (tid >= kB * kD) return;
  int b = tid >> 6, d = tid & 63;
  float p = uacc[tid] * iacc[tid];
  for (int o = 32; o > 0; o >>= 1) p += __shfl_down(p, o, 64);
  if (d == 0) out[b] = p * 0.0625f;
}

}  // namespace

extern "C" void kernel_launch(void* const* d_in, const int* in_sizes, int n_in,
                              void* d_out, int out_size, void* d_ws, size_t ws_size,
                              hipStream_t stream) {
  const int*   users = (const int*)d_in[0];
  const int*   items = (const int*)d_in[1];
  const int*   erow  = (const int*)d_in[2];
  const int*   ecol  = (const int*)d_in[3];
  const float* evals = (const float*)d_in[4];
  const float* uemb  = (const float*)d_in[5];
  const float* iemb  = (const float*)d_in[6];
  float* out = (float*)d_out;

  char* ws = (char*)d_ws;
  size_t off = 0;
  auto take = [&](size_t bytes) -> char* {
    char* p = ws + off;
    off = (off + bytes + 255) & ~(size_t)255;
    return p;
  };
  int*   rowptr = (int*)take((size_t)(kN + 1) * 4);
  int*   bcnt   = (int*)take((kNBKT + 1) * 4);
  int*   bbase  = (int*)take((kNBKT + 1) * 4);
  int*   gpos   = (int*)take((kNBKT + 1) * 4);
  int2*  edges  = (int2*)take((size_t)kNNZ * 8);
  float* xA     = (float*)take((size_t)kN * kD * 4);
  float* xB     = (float*)take((size_t)kN * kD * 4);
  float* uacc   = (float*)take((size_t)kB * kD * 4);
  float* iacc   = (float*)take((size_t)kB * kD * 4);
  int2*  tmp    = (int2*)xA;   // 40 MB, dead before spmm<true> writes xA
  (void)ws_size; (void)in_sizes; (void)n_in; (void)out_size;

  const int nScatBlocks = (kNNZ + kEPB - 1) / kEPB;   // 2442

  // --- CSR build via two-level bucketing (no global random scatter) ---
  zero_i32<<<1, 256, 0, stream>>>(bcnt, kNBKT + 1);
  bin_count<<<nScatBlocks, 256, 0, stream>>>(erow, bcnt);
  bucket_scan<<<1, 256, 0, stream>>>(bcnt, bbase, gpos);
  bucket_scatter<<<nScatBlocks, 256, 0, stream>>>(erow, ecol, evals, gpos, tmp);
  bucket_finalize<<<kNBKT, 256, 0, stream>>>(bbase, tmp, rowptr, edges);

  // --- acc = all_emb term for the selected pairs ---
  acc_init<<<(kB * kD) / 256, 256, 0, stream>>>(users, items, uemb, iemb, uacc, iacc);

  // --- 3 propagation layers, ping-pong xA/xB ---
  spmm<true ><<<kN / 4, 256, 0, stream>>>(rowptr, edges, nullptr, uemb, iemb, xA);
  acc_add<<<(kB * kD) / 256, 256, 0, stream>>>(users, items, xA, uacc, iacc);
  spmm<false><<<kN / 4, 256, 0, stream>>>(rowptr, edges, xA, uemb, iemb, xB);
  acc_add<<<(kB * kD) / 256, 256, 0, stream>>>(users, items, xB, uacc, iacc);
  spmm<false><<<kN / 4, 256, 0, stream>>>(rowptr, edges, xB, uemb, iemb, xA);
  acc_add<<<(kB * kD) / 256, 256, 0, stream>>>(users, items, xA, uacc, iacc);

  finalize<<<(kB * kD) / 256, 256, 0, stream>>>(uacc, iacc, out);
}

// Round 4
// 931.180 us; speedup vs baseline: 2.1710x; 1.0558x over previous
//
#include <hip/hip_runtime.h>

namespace {

constexpr int kUsers = 100000;
constexpr int kItems = 200000;
constexpr int kN     = kUsers + kItems;   // 300000
constexpr int kD     = 64;
constexpr int kNNZ   = 5000000;
constexpr int kB     = 16384;
constexpr int kRowsPerBkt = 2048;                       // rows per coarse bucket
constexpr int kNBKT  = (kN + kRowsPerBkt - 1) / kRowsPerBkt;  // 147
constexpr int kEPB   = 2048;                            // edges per bin_count block
constexpr int kSEPB  = 4096;                            // edges per bucket_scatter block
constexpr int kCE    = 8192;                            // edges per finalize chunk
constexpr int kMC    = 6;                               // max chunks per bucket (49152 cap >> ~34.8k max)

__global__ void zero_i32(int* __restrict__ p, int n) {
  int i = blockIdx.x * blockDim.x + threadIdx.x;
  if (i < n) p[i] = 0;
}

// Per-block LDS histogram of coarse buckets, flushed with one atomic per bucket.
__global__ void bin_count(const int* __restrict__ row, int* __restrict__ bcnt) {
  __shared__ int h[kNBKT];
  int t = threadIdx.x;
  for (int i = t; i < kNBKT; i += 256) h[i] = 0;
  __syncthreads();
  long base = (long)blockIdx.x * kEPB + t;
#pragma unroll
  for (int j = 0; j < 8; ++j) {
    long i = base + j * 256;
    if (i < kNNZ) atomicAdd(&h[row[i] >> 11], 1);
  }
  __syncthreads();
  for (int i = t; i < kNBKT; i += 256)
    if (h[i]) atomicAdd(&bcnt[i], h[i]);
}

// Exclusive scan of 147 bucket counts; bbase[kNBKT] = total; gpos = running cursors.
__global__ void bucket_scan(const int* __restrict__ bcnt, int* __restrict__ bbase,
                            int* __restrict__ gpos) {
  __shared__ int lds[256];
  int t = threadIdx.x;
  lds[t] = (t < kNBKT) ? bcnt[t] : 0;
  __syncthreads();
  for (int o = 1; o < 256; o <<= 1) {
    int v = (t >= o) ? lds[t - o] : 0;
    __syncthreads();
    if (t >= o) lds[t] += v;
    __syncthreads();
  }
  int ex = (t == 0) ? 0 : lds[t - 1];
  if (t < kNBKT) { bbase[t] = ex; gpos[t] = ex; }
  if (t == kNBKT) bbase[t] = ex;   // == kNNZ
}

// Bin 4096 edges into coarse buckets: local LDS ranks + per-bucket global
// reservation -> block-contiguous runs (~28 edges = 224B each) in tmp.
// Packed edge: .x = (rowlocal<<19)|col, .y = val bits.
__global__ void bucket_scatter(const int* __restrict__ row, const int* __restrict__ col,
                               const float* __restrict__ val, int* __restrict__ gpos,
                               int2* __restrict__ tmp) {
  __shared__ int hcnt[kNBKT];
  __shared__ int hbase[kNBKT];
  int t = threadIdx.x;
  long base = (long)blockIdx.x * kSEPB;
  for (int i = t; i < kNBKT; i += 256) hcnt[i] = 0;
  __syncthreads();
  int pk[16], bk[16], rk[16];
  float v[16];
  bool ok[16];
#pragma unroll
  for (int j = 0; j < 16; ++j) {
    long i = base + j * 256 + t;
    ok[j] = (i < kNNZ);
    if (ok[j]) {
      int r = row[i];
      bk[j] = r >> 11;
      pk[j] = ((r & 2047) << 19) | col[i];
      v[j] = val[i];
      rk[j] = atomicAdd(&hcnt[bk[j]], 1);
    }
  }
  __syncthreads();
  for (int i = t; i < kNBKT; i += 256) hbase[i] = atomicAdd(&gpos[i], hcnt[i]);
  __syncthreads();
#pragma unroll
  for (int j = 0; j < 16; ++j)
    if (ok[j]) tmp[hbase[bk[j]] + rk[j]] = make_int2(pk[j], __float_as_int(v[j]));
}

// Grid = kNBKT*kMC. Per-(bucket,chunk) 2048-row LDS histogram -> ctab.
__global__ void chunk_hist(const int* __restrict__ bbase, const int2* __restrict__ tmp,
                           int* __restrict__ ctab) {
  __shared__ int h[kRowsPerBkt];
  int b = blockIdx.x / kMC, c = blockIdx.x % kMC;
  int t = threadIdx.x;
  for (int i = t; i < kRowsPerBkt; i += 256) h[i] = 0;
  __syncthreads();
  int s = bbase[b] + c * kCE;
  int e = bbase[b + 1];
  if (s + kCE < e) e = s + kCE;
  for (int j = s + t; j < e; j += 256) atomicAdd(&h[tmp[j].x >> 19], 1);
  __syncthreads();
  int* dst = ctab + (size_t)blockIdx.x * kRowsPerBkt;
  for (int i = t; i < kRowsPerBkt; i += 256) dst[i] = h[i];
}

// Block b: per-row total over kMC chunks (replacing ctab entries with the
// exclusive prefix over chunks), then block-scan 2048 row totals -> chunk-local
// rowptr + per-bucket partial.
__global__ void scanA(int* __restrict__ ctab, int* __restrict__ rowptr,
                      int* __restrict__ partials) {
  __shared__ int lsum[256];
  int b = blockIdx.x, t = threadIdx.x;
  int cnt[8];
#pragma unroll
  for (int k = 0; k < 8; ++k) cnt[k] = 0;
  for (int c = 0; c < kMC; ++c) {
    int* p = ctab + (size_t)(b * kMC + c) * kRowsPerBkt;
#pragma unroll
    for (int k = 0; k < 8; ++k) {
      int idx = t * 8 + k;
      int v = p[idx];
      p[idx] = cnt[k];       // exclusive prefix over chunks
      cnt[k] += v;
    }
  }
  int s = 0, pref[8];
#pragma unroll
  for (int k = 0; k < 8; ++k) { pref[k] = s; s += cnt[k]; }
  lsum[t] = s;
  __syncthreads();
  for (int o = 1; o < 256; o <<= 1) {
    int v = (t >= o) ? lsum[t - o] : 0;
    __syncthreads();
    if (t >= o) lsum[t] += v;
    __syncthreads();
  }
  int ex = (t == 0) ? 0 : lsum[t - 1];
#pragma unroll
  for (int k = 0; k < 8; ++k) {
    int r = b * kRowsPerBkt + t * 8 + k;
    if (r < kN) rowptr[r] = ex + pref[k];
  }
  if (t == 255) partials[b] = lsum[255];
}

// Exclusive scan of the 147 bucket partials, in place.
__global__ void scan2(int* __restrict__ partials) {
  __shared__ int lds[256];
  int t = threadIdx.x;
  lds[t] = (t < kNBKT) ? partials[t] : 0;
  __syncthreads();
  for (int o = 1; o < 256; o <<= 1) {
    int v = (t >= o) ? lds[t - o] : 0;
    __syncthreads();
    if (t >= o) lds[t] += v;
    __syncthreads();
  }
  int ex = (t == 0) ? 0 : lds[t - 1];
  if (t < kNBKT) partials[t] = ex;
}

__global__ void scan3(int* __restrict__ rowptr, const int* __restrict__ partials) {
  int i = blockIdx.x * blockDim.x + threadIdx.x;
  if (i < kN) rowptr[i] += partials[i >> 11];
  else if (i == kN) rowptr[kN] = kNNZ;
}

// Grid = kNBKT*kMC. Stable-ish placement: LDS rank within chunk, destination
// rowptr[r] + ctab(chunk-excl) + rank. Random writes confined to the bucket's
// ~272 KB window.
__global__ void chunk_place(const int* __restrict__ bbase, const int2* __restrict__ tmp,
                            const int* __restrict__ rowptr, const int* __restrict__ ctab,
                            int2* __restrict__ edges) {
  __shared__ int rank[kRowsPerBkt];
  int b = blockIdx.x / kMC, c = blockIdx.x % kMC;
  int t = threadIdx.x;
  for (int i = t; i < kRowsPerBkt; i += 256) rank[i] = 0;
  __syncthreads();
  int s = bbase[b] + c * kCE;
  int e = bbase[b + 1];
  if (s + kCE < e) e = s + kCE;
  const int* coff = ctab + (size_t)blockIdx.x * kRowsPerBkt;
  for (int j = s + t; j < e; j += 256) {
    int2 epk = tmp[j];
    int rl = epk.x >> 19;
    int k = atomicAdd(&rank[rl], 1);
    int dst = rowptr[b * kRowsPerBkt + rl] + coff[rl] + k;
    edges[dst] = make_int2(epk.x & 0x7FFFF, epk.y);
  }
}

// One wave per row. 4 edge slots x 16 dim-lanes (float4), unrolled x2 with two
// accumulators -> 8 independent 256B row-gathers in flight per wave.
template <bool FIRST>
__global__ void spmm(const int* __restrict__ rowptr, const int2* __restrict__ edges,
                     const float* __restrict__ x, const float* __restrict__ uemb,
                     const float* __restrict__ iemb, float* __restrict__ y) {
  int wave = threadIdx.x >> 6;
  int lane = threadIdx.x & 63;
  int eslot = lane >> 4;
  int l16 = lane & 15;
  int r = blockIdx.x * 4 + wave;
  if (r >= kN) return;
  int s = rowptr[r], e = rowptr[r + 1];
  float4 sum0 = make_float4(0.f, 0.f, 0.f, 0.f);
  float4 sum1 = make_float4(0.f, 0.f, 0.f, 0.f);
  auto addr = [&](int c) -> const float* {
    if (FIRST)
      return (c < kUsers) ? (uemb + (size_t)c * kD) : (iemb + (size_t)(c - kUsers) * kD);
    return x + (size_t)c * kD;
  };
  int j = s + eslot;
  for (; j + 4 < e; j += 8) {
    int2 e0 = edges[j];
    int2 e1 = edges[j + 4];
    float4 x0 = ((const float4*)addr(e0.x))[l16];
    float4 x1 = ((const float4*)addr(e1.x))[l16];
    float v0 = __int_as_float(e0.y), v1 = __int_as_float(e1.y);
    sum0.x += v0 * x0.x; sum0.y += v0 * x0.y; sum0.z += v0 * x0.z; sum0.w += v0 * x0.w;
    sum1.x += v1 * x1.x; sum1.y += v1 * x1.y; sum1.z += v1 * x1.z; sum1.w += v1 * x1.w;
  }
  if (j < e) {
    int2 e0 = edges[j];
    float4 x0 = ((const float4*)addr(e0.x))[l16];
    float v0 = __int_as_float(e0.y);
    sum0.x += v0 * x0.x; sum0.y += v0 * x0.y; sum0.z += v0 * x0.z; sum0.w += v0 * x0.w;
  }
  sum0.x += sum1.x; sum0.y += sum1.y; sum0.z += sum1.z; sum0.w += sum1.w;
#pragma unroll
  for (int m = 16; m <= 32; m <<= 1) {
    sum0.x += __shfl_xor(sum0.x, m, 64);
    sum0.y += __shfl_xor(sum0.y, m, 64);
    sum0.z += __shfl_xor(sum0.z, m, 64);
    sum0.w += __shfl_xor(sum0.w, m, 64);
  }
  if (eslot == 0) ((float4*)y)[(size_t)r * 16 + l16] = sum0;
}

__global__ void acc_init(const int* __restrict__ users, const int* __restrict__ items,
                         const float* __restrict__ uemb, const float* __restrict__ iemb,
                         float* __restrict__ uacc, float* __restrict__ iacc) {
  int tid = blockIdx.x * blockDim.x + threadIdx.x;
  if (tid >= kB * kD) return;
  int b = tid >> 6, d = tid & 63;
  uacc[tid] = uemb[(size_t)users[b] * kD + d];
  iacc[tid] = iemb[(size_t)items[b] * kD + d];
}

__global__ void acc_add(const int* __restrict__ users, const int* __restrict__ items,
                        const float* __restrict__ x, float* __restrict__ uacc,
                        float* __restrict__ iacc) {
  int tid = blockIdx.x * blockDim.x + threadIdx.x;
  if (tid >= kB * kD) return;
  int b = tid >> 6, d = tid & 63;
  uacc[tid] += x[(size_t)users[b] * kD + d];
  iacc[tid] += x[(size_t)(kUsers + items[b]) * kD + d];
}

// gamma[b] = dot(acc_u, acc_i) / 16
__global__ void finalize(const float* __restrict__ uacc, const float* __restrict__ iacc,
                         float* __restrict__ out) {
  int tid = blockIdx.x * blockDim.x + threadIdx.x;
  if (tid >= kB * kD) return;
  int b = tid >> 6, d = tid & 63;
  float p = uacc[tid] * iacc[tid];
  for (int o = 32; o > 0; o >>= 1) p += __shfl_down(p, o, 64);
  if (d == 0) out[b] = p * 0.0625f;
}

}  // namespace

extern "C" void kernel_launch(void* const* d_in, const int* in_sizes, int n_in,
                              void* d_out, int out_size, void* d_ws, size_t ws_size,
                              hipStream_t stream) {
  const int*   users = (const int*)d_in[0];
  const int*   items = (const int*)d_in[1];
  const int*   erow  = (const int*)d_in[2];
  const int*   ecol  = (const int*)d_in[3];
  const float* evals = (const float*)d_in[4];
  const float* uemb  = (const float*)d_in[5];
  const float* iemb  = (const float*)d_in[6];
  float* out = (float*)d_out;

  char* ws = (char*)d_ws;
  size_t off = 0;
  auto take = [&](size_t bytes) -> char* {
    char* p = ws + off;
    off = (off + bytes + 255) & ~(size_t)255;
    return p;
  };
  int*   rowptr = (int*)take((size_t)(kN + 1) * 4);
  int*   bcnt   = (int*)take((kNBKT + 1) * 4);
  int*   bbase  = (int*)take((kNBKT + 1) * 4);
  int*   gpos   = (int*)take((kNBKT + 1) * 4);
  int*   partials = (int*)take(256 * 4);
  int2*  edges  = (int2*)take((size_t)kNNZ * 8);
  float* xA     = (float*)take((size_t)kN * kD * 4);
  float* xB     = (float*)take((size_t)kN * kD * 4);
  float* uacc   = (float*)take((size_t)kB * kD * 4);
  float* iacc   = (float*)take((size_t)kB * kD * 4);
  int2*  tmp    = (int2*)xA;   // 40 MB, dead before spmm<true> writes xA
  int*   ctab   = (int*)xB;    // 7.2 MB, dead before spmm #2 writes xB
  (void)ws_size; (void)in_sizes; (void)n_in; (void)out_size;

  const int nBinBlocks  = (kNNZ + kEPB - 1) / kEPB;    // 2442
  const int nScatBlocks = (kNNZ + kSEPB - 1) / kSEPB;  // 1221

  // --- CSR build: coarse bucket sort, then parallel per-chunk counting sort ---
  zero_i32<<<1, 256, 0, stream>>>(bcnt, kNBKT + 1);
  bin_count<<<nBinBlocks, 256, 0, stream>>>(erow, bcnt);
  bucket_scan<<<1, 256, 0, stream>>>(bcnt, bbase, gpos);
  bucket_scatter<<<nScatBlocks, 256, 0, stream>>>(erow, ecol, evals, gpos, tmp);
  chunk_hist<<<kNBKT * kMC, 256, 0, stream>>>(bbase, tmp, ctab);
  scanA<<<kNBKT, 256, 0, stream>>>(ctab, rowptr, partials);
  scan2<<<1, 256, 0, stream>>>(partials);
  scan3<<<(kN + 1 + 255) / 256, 256, 0, stream>>>(rowptr, partials);
  chunk_place<<<kNBKT * kMC, 256, 0, stream>>>(bbase, tmp, rowptr, ctab, edges);

  // --- acc = all_emb term for the selected pairs ---
  acc_init<<<(kB * kD) / 256, 256, 0, stream>>>(users, items, uemb, iemb, uacc, iacc);

  // --- 3 propagation layers, ping-pong xA/xB ---
  spmm<true ><<<kN / 4, 256, 0, stream>>>(rowptr, edges, nullptr, uemb, iemb, xA);
  acc_add<<<(kB * kD) / 256, 256, 0, stream>>>(users, items, xA, uacc, iacc);
  spmm<false><<<kN / 4, 256, 0, stream>>>(rowptr, edges, xA, uemb, iemb, xB);
  acc_add<<<(kB * kD) / 256, 256, 0, stream>>>(users, items, xB, uacc, iacc);
  spmm<false><<<kN / 4, 256, 0, stream>>>(rowptr, edges, xB, uemb, iemb, xA);
  acc_add<<<(kB * kD) / 256, 256, 0, stream>>>(users, items, xA, uacc, iacc);

  finalize<<<(kB * kD) / 256, 256, 0, stream>>>(uacc, iacc, out);
}

// Round 5
// 822.079 us; speedup vs baseline: 2.4591x; 1.1327x over previous
//
#include <hip/hip_runtime.h>
#include <hip/hip_fp16.h>

namespace {

constexpr int kUsers = 100000;
constexpr int kItems = 200000;
constexpr int kN     = kUsers + kItems;   // 300000
constexpr int kD     = 64;
constexpr int kNNZ   = 5000000;
constexpr int kB     = 16384;
constexpr int kRowsPerBkt = 2048;                       // rows per coarse bucket
constexpr int kNBKT  = (kN + kRowsPerBkt - 1) / kRowsPerBkt;  // 147
constexpr int kEPB   = 2048;                            // edges per bin_count block
constexpr int kSEPB  = 4096;                            // edges per bucket_scatter block
constexpr int kCE    = 8192;                            // edges per finalize chunk
constexpr int kMC    = 6;                               // max chunks per bucket

__global__ void zero_i32(int* __restrict__ p, int n) {
  int i = blockIdx.x * blockDim.x + threadIdx.x;
  if (i < n) p[i] = 0;
}

// Per-block LDS histogram of coarse buckets, flushed with one atomic per bucket.
__global__ void bin_count(const int* __restrict__ row, int* __restrict__ bcnt) {
  __shared__ int h[kNBKT];
  int t = threadIdx.x;
  for (int i = t; i < kNBKT; i += 256) h[i] = 0;
  __syncthreads();
  long base = (long)blockIdx.x * kEPB + t;
#pragma unroll
  for (int j = 0; j < 8; ++j) {
    long i = base + j * 256;
    if (i < kNNZ) atomicAdd(&h[row[i] >> 11], 1);
  }
  __syncthreads();
  for (int i = t; i < kNBKT; i += 256)
    if (h[i]) atomicAdd(&bcnt[i], h[i]);
}

__global__ void bucket_scan(const int* __restrict__ bcnt, int* __restrict__ bbase,
                            int* __restrict__ gpos) {
  __shared__ int lds[256];
  int t = threadIdx.x;
  lds[t] = (t < kNBKT) ? bcnt[t] : 0;
  __syncthreads();
  for (int o = 1; o < 256; o <<= 1) {
    int v = (t >= o) ? lds[t - o] : 0;
    __syncthreads();
    if (t >= o) lds[t] += v;
    __syncthreads();
  }
  int ex = (t == 0) ? 0 : lds[t - 1];
  if (t < kNBKT) { bbase[t] = ex; gpos[t] = ex; }
  if (t == kNBKT) bbase[t] = ex;   // == kNNZ
}

// Bin 4096 edges into coarse buckets -> block-contiguous runs in tmp.
// Packed edge: .x = (rowlocal<<19)|col, .y = val bits.
__global__ void bucket_scatter(const int* __restrict__ row, const int* __restrict__ col,
                               const float* __restrict__ val, int* __restrict__ gpos,
                               int2* __restrict__ tmp) {
  __shared__ int hcnt[kNBKT];
  __shared__ int hbase[kNBKT];
  int t = threadIdx.x;
  long base = (long)blockIdx.x * kSEPB;
  for (int i = t; i < kNBKT; i += 256) hcnt[i] = 0;
  __syncthreads();
  int pk[16], bk[16], rk[16];
  float v[16];
  bool ok[16];
#pragma unroll
  for (int j = 0; j < 16; ++j) {
    long i = base + j * 256 + t;
    ok[j] = (i < kNNZ);
    if (ok[j]) {
      int r = row[i];
      bk[j] = r >> 11;
      pk[j] = ((r & 2047) << 19) | col[i];
      v[j] = val[i];
      rk[j] = atomicAdd(&hcnt[bk[j]], 1);
    }
  }
  __syncthreads();
  for (int i = t; i < kNBKT; i += 256) hbase[i] = atomicAdd(&gpos[i], hcnt[i]);
  __syncthreads();
#pragma unroll
  for (int j = 0; j < 16; ++j)
    if (ok[j]) tmp[hbase[bk[j]] + rk[j]] = make_int2(pk[j], __float_as_int(v[j]));
}

// Grid = kNBKT*kMC. Per-(bucket,chunk) 2048-row LDS histogram -> ctab.
__global__ void chunk_hist(const int* __restrict__ bbase, const int2* __restrict__ tmp,
                           int* __restrict__ ctab) {
  __shared__ int h[kRowsPerBkt];
  int b = blockIdx.x / kMC, c = blockIdx.x % kMC;
  int t = threadIdx.x;
  for (int i = t; i < kRowsPerBkt; i += 256) h[i] = 0;
  __syncthreads();
  int s = bbase[b] + c * kCE;
  int e = bbase[b + 1];
  if (s + kCE < e) e = s + kCE;
  for (int j = s + t; j < e; j += 256) atomicAdd(&h[tmp[j].x >> 19], 1);
  __syncthreads();
  int* dst = ctab + (size_t)blockIdx.x * kRowsPerBkt;
  for (int i = t; i < kRowsPerBkt; i += 256) dst[i] = h[i];
}

// Per-row totals over chunks (ctab -> chunk-exclusive prefixes), block-scan of
// 2048 row totals -> bucket-local rowptr + per-bucket partial.
__global__ void scanA(int* __restrict__ ctab, int* __restrict__ rowptr,
                      int* __restrict__ partials) {
  __shared__ int lsum[256];
  int b = blockIdx.x, t = threadIdx.x;
  int cnt[8];
#pragma unroll
  for (int k = 0; k < 8; ++k) cnt[k] = 0;
  for (int c = 0; c < kMC; ++c) {
    int* p = ctab + (size_t)(b * kMC + c) * kRowsPerBkt;
#pragma unroll
    for (int k = 0; k < 8; ++k) {
      int idx = t * 8 + k;
      int v = p[idx];
      p[idx] = cnt[k];
      cnt[k] += v;
    }
  }
  int s = 0, pref[8];
#pragma unroll
  for (int k = 0; k < 8; ++k) { pref[k] = s; s += cnt[k]; }
  lsum[t] = s;
  __syncthreads();
  for (int o = 1; o < 256; o <<= 1) {
    int v = (t >= o) ? lsum[t - o] : 0;
    __syncthreads();
    if (t >= o) lsum[t] += v;
    __syncthreads();
  }
  int ex = (t == 0) ? 0 : lsum[t - 1];
#pragma unroll
  for (int k = 0; k < 8; ++k) {
    int r = b * kRowsPerBkt + t * 8 + k;
    if (r < kN) rowptr[r] = ex + pref[k];
  }
  if (t == 255) partials[b] = lsum[255];
}

__global__ void scan2(int* __restrict__ partials) {
  __shared__ int lds[256];
  int t = threadIdx.x;
  lds[t] = (t < kNBKT) ? partials[t] : 0;
  __syncthreads();
  for (int o = 1; o < 256; o <<= 1) {
    int v = (t >= o) ? lds[t - o] : 0;
    __syncthreads();
    if (t >= o) lds[t] += v;
    __syncthreads();
  }
  int ex = (t == 0) ? 0 : lds[t - 1];
  if (t < kNBKT) partials[t] = ex;
}

__global__ void scan3(int* __restrict__ rowptr, const int* __restrict__ partials) {
  int i = blockIdx.x * blockDim.x + threadIdx.x;
  if (i < kN) rowptr[i] += partials[i >> 11];
  else if (i == kN) rowptr[kN] = kNNZ;
}

// Grid = kNBKT*kMC. Place edges to final CSR slots; random writes confined to
// the bucket's ~272 KB window.
__global__ void chunk_place(const int* __restrict__ bbase, const int2* __restrict__ tmp,
                            const int* __restrict__ rowptr, const int* __restrict__ ctab,
                            int2* __restrict__ edges) {
  __shared__ int rank[kRowsPerBkt];
  int b = blockIdx.x / kMC, c = blockIdx.x % kMC;
  int t = threadIdx.x;
  for (int i = t; i < kRowsPerBkt; i += 256) rank[i] = 0;
  __syncthreads();
  int s = bbase[b] + c * kCE;
  int e = bbase[b + 1];
  if (s + kCE < e) e = s + kCE;
  const int* coff = ctab + (size_t)blockIdx.x * kRowsPerBkt;
  for (int j = s + t; j < e; j += 256) {
    int2 epk = tmp[j];
    int rl = epk.x >> 19;
    int k = atomicAdd(&rank[rl], 1);
    int dst = rowptr[b * kRowsPerBkt + rl] + coff[rl] + k;
    edges[dst] = make_int2(epk.x & 0x7FFFF, epk.y);
  }
}

// Convert concat(uemb, iemb) rows to fp16. One thread per 4 elems.
__global__ void to_half(const float* __restrict__ ue, const float* __restrict__ ie,
                        __half* __restrict__ xh) {
  int t = blockIdx.x * blockDim.x + threadIdx.x;
  if (t >= kN * kD / 4) return;
  int row = t >> 4;              // 16 float4-groups per row
  int g = t & 15;
  const float* src = (row < kUsers) ? (ue + (size_t)row * kD)
                                    : (ie + (size_t)(row - kUsers) * kD);
  float4 v = ((const float4*)src)[g];
  __half2 h01 = __float22half2_rn(make_float2(v.x, v.y));
  __half2 h23 = __float22half2_rn(make_float2(v.z, v.w));
  int2 pk = make_int2(*(int*)&h01, *(int*)&h23);
  ((int2*)xh)[t] = pk;
}

// One wave per row. 4 edge slots x 16 dim-lanes; fp16 gathers (128 B/row),
// fp32 accumulate; unrolled x4 -> 16 independent row-gathers in flight.
// Writes fp32 y (for exact acc path) and fp16 yh (for the next layer).
__global__ void spmm(const int* __restrict__ rowptr, const int2* __restrict__ edges,
                     const __half* __restrict__ x, float* __restrict__ y,
                     __half* __restrict__ yh) {
  int wave = threadIdx.x >> 6;
  int lane = threadIdx.x & 63;
  int eslot = lane >> 4;
  int l16 = lane & 15;
  int r = blockIdx.x * 4 + wave;
  if (r >= kN) return;
  int s = rowptr[r], e = rowptr[r + 1];
  float4 a0 = make_float4(0.f, 0.f, 0.f, 0.f);
  float4 a1 = make_float4(0.f, 0.f, 0.f, 0.f);
  float4 a2 = make_float4(0.f, 0.f, 0.f, 0.f);
  float4 a3 = make_float4(0.f, 0.f, 0.f, 0.f);
  auto fmadd = [&](float4& acc, int2 epk) {
    int2 hv = ((const int2*)(x + (size_t)epk.x * kD))[l16];
    float v = __int_as_float(epk.y);
    float2 f01 = __half22float2(*(__half2*)&hv.x);
    float2 f23 = __half22float2(*(__half2*)&hv.y);
    acc.x += v * f01.x; acc.y += v * f01.y;
    acc.z += v * f23.x; acc.w += v * f23.y;
  };
  int j = s + eslot;
  for (; j + 12 < e; j += 16) {
    int2 e0 = edges[j];
    int2 e1 = edges[j + 4];
    int2 e2 = edges[j + 8];
    int2 e3 = edges[j + 12];
    fmadd(a0, e0); fmadd(a1, e1); fmadd(a2, e2); fmadd(a3, e3);
  }
  for (; j < e; j += 4) fmadd(a0, edges[j]);
  a0.x += a1.x + a2.x + a3.x;
  a0.y += a1.y + a2.y + a3.y;
  a0.z += a1.z + a2.z + a3.z;
  a0.w += a1.w + a2.w + a3.w;
#pragma unroll
  for (int m = 16; m <= 32; m <<= 1) {
    a0.x += __shfl_xor(a0.x, m, 64);
    a0.y += __shfl_xor(a0.y, m, 64);
    a0.z += __shfl_xor(a0.z, m, 64);
    a0.w += __shfl_xor(a0.w, m, 64);
  }
  if (eslot == 0) {
    ((float4*)y)[(size_t)r * 16 + l16] = a0;
    __half2 h01 = __float22half2_rn(make_float2(a0.x, a0.y));
    __half2 h23 = __float22half2_rn(make_float2(a0.z, a0.w));
    ((int2*)yh)[(size_t)r * 16 + l16] = make_int2(*(int*)&h01, *(int*)&h23);
  }
}

__global__ void acc_init(const int* __restrict__ users, const int* __restrict__ items,
                         const float* __restrict__ uemb, const float* __restrict__ iemb,
                         float* __restrict__ uacc, float* __restrict__ iacc) {
  int tid = blockIdx.x * blockDim.x + threadIdx.x;
  if (tid >= kB * kD) return;
  int b = tid >> 6, d = tid & 63;
  uacc[tid] = uemb[(size_t)users[b] * kD + d];
  iacc[tid] = iemb[(size_t)items[b] * kD + d];
}

__global__ void acc_add(const int* __restrict__ users, const int* __restrict__ items,
                        const float* __restrict__ x, float* __restrict__ uacc,
                        float* __restrict__ iacc) {
  int tid = blockIdx.x * blockDim.x + threadIdx.x;
  if (tid >= kB * kD) return;
  int b = tid >> 6, d = tid & 63;
  uacc[tid] += x[(size_t)users[b] * kD + d];
  iacc[tid] += x[(size_t)(kUsers + items[b]) * kD + d];
}

// gamma[b] = dot(acc_u, acc_i) / 16
__global__ void finalize(const float* __restrict__ uacc, const float* __restrict__ iacc,
                         float* __restrict__ out) {
  int tid = blockIdx.x * blockDim.x + threadIdx.x;
  if (tid >= kB * kD) return;
  int b = tid >> 6, d = tid & 63;
  float p = uacc[tid] * iacc[tid];
  for (int o = 32; o > 0; o >>= 1) p += __shfl_down(p, o, 64);
  if (d == 0) out[b] = p * 0.0625f;
}

}  // namespace

extern "C" void kernel_launch(void* const* d_in, const int* in_sizes, int n_in,
                              void* d_out, int out_size, void* d_ws, size_t ws_size,
                              hipStream_t stream) {
  const int*   users = (const int*)d_in[0];
  const int*   items = (const int*)d_in[1];
  const int*   erow  = (const int*)d_in[2];
  const int*   ecol  = (const int*)d_in[3];
  const float* evals = (const float*)d_in[4];
  const float* uemb  = (const float*)d_in[5];
  const float* iemb  = (const float*)d_in[6];
  float* out = (float*)d_out;

  char* ws = (char*)d_ws;
  size_t off = 0;
  auto take = [&](size_t bytes) -> char* {
    char* p = ws + off;
    off = (off + bytes + 255) & ~(size_t)255;
    return p;
  };
  int*    rowptr   = (int*)take((size_t)(kN + 1) * 4);
  int*    bcnt     = (int*)take((kNBKT + 1) * 4);
  int*    bbase    = (int*)take((kNBKT + 1) * 4);
  int*    gpos     = (int*)take((kNBKT + 1) * 4);
  int*    partials = (int*)take(256 * 4);
  int2*   edges    = (int2*)take((size_t)kNNZ * 8);
  float*  yF       = (float*)take((size_t)kN * kD * 4);   // fp32 y, reused per layer
  __half* xh0      = (__half*)take((size_t)kN * kD * 2);  // fp16 ping
  __half* xh1      = (__half*)take((size_t)kN * kD * 2);  // fp16 pong
  float*  uacc     = (float*)take((size_t)kB * kD * 4);
  float*  iacc     = (float*)take((size_t)kB * kD * 4);
  int2*   tmp      = (int2*)yF;    // 40 MB, dead before spmm #1 writes yF
  int*    ctab     = (int*)xh0;    // 7.2 MB, dead before to_half writes xh0
  (void)ws_size; (void)in_sizes; (void)n_in; (void)out_size;

  const int nBinBlocks  = (kNNZ + kEPB - 1) / kEPB;    // 2442
  const int nScatBlocks = (kNNZ + kSEPB - 1) / kSEPB;  // 1221

  // --- CSR build: coarse bucket sort, then parallel per-chunk counting sort ---
  zero_i32<<<1, 256, 0, stream>>>(bcnt, kNBKT + 1);
  bin_count<<<nBinBlocks, 256, 0, stream>>>(erow, bcnt);
  bucket_scan<<<1, 256, 0, stream>>>(bcnt, bbase, gpos);
  bucket_scatter<<<nScatBlocks, 256, 0, stream>>>(erow, ecol, evals, gpos, tmp);
  chunk_hist<<<kNBKT * kMC, 256, 0, stream>>>(bbase, tmp, ctab);
  scanA<<<kNBKT, 256, 0, stream>>>(ctab, rowptr, partials);
  scan2<<<1, 256, 0, stream>>>(partials);
  scan3<<<(kN + 1 + 255) / 256, 256, 0, stream>>>(rowptr, partials);
  chunk_place<<<kNBKT * kMC, 256, 0, stream>>>(bbase, tmp, rowptr, ctab, edges);

  // --- fp16 copy of concat embeddings (after chunk_place: ctab aliases xh0) ---
  to_half<<<(kN * kD / 4 + 255) / 256, 256, 0, stream>>>(uemb, iemb, xh0);
  acc_init<<<(kB * kD) / 256, 256, 0, stream>>>(users, items, uemb, iemb, uacc, iacc);

  // --- 3 propagation layers; fp16 ping-pong for gathers, fp32 y for acc ---
  spmm<<<kN / 4, 256, 0, stream>>>(rowptr, edges, xh0, yF, xh1);
  acc_add<<<(kB * kD) / 256, 256, 0, stream>>>(users, items, yF, uacc, iacc);
  spmm<<<kN / 4, 256, 0, stream>>>(rowptr, edges, xh1, yF, xh0);
  acc_add<<<(kB * kD) / 256, 256, 0, stream>>>(users, items, yF, uacc, iacc);
  spmm<<<kN / 4, 256, 0, stream>>>(rowptr, edges, xh0, yF, xh1);
  acc_add<<<(kB * kD) / 256, 256, 0, stream>>>(users, items, yF, uacc, iacc);

  finalize<<<(kB * kD) / 256, 256, 0, stream>>>(uacc, iacc, out);
}

// Round 6
// 728.677 us; speedup vs baseline: 2.7743x; 1.1282x over previous
//
#include <hip/hip_runtime.h>
#include <hip/hip_fp16.h>

namespace {

constexpr int kUsers = 100000;
constexpr int kItems = 200000;
constexpr int kN     = kUsers + kItems;   // 300000
constexpr int kD     = 64;
constexpr int kNNZ   = 5000000;
constexpr int kB     = 16384;
constexpr int kRowsPerBkt = 2048;                       // rows per coarse bucket
constexpr int kNBKT  = (kN + kRowsPerBkt - 1) / kRowsPerBkt;  // 147
constexpr int kSEPB  = 4096;                            // edges per bucket_scatter block
constexpr int kCE    = 8192;                            // edges per finalize chunk
constexpr int kMC    = 5;                               // chunks per bucket
constexpr int kCap   = kMC * kCE;                       // 40960 slots/bucket (mean 34133, sd 185)

__global__ void zero_i32(int* __restrict__ p, int n) {
  int i = blockIdx.x * blockDim.x + threadIdx.x;
  if (i < n) p[i] = 0;
}

// Counting-sort partition of 4096 edges into 147 coarse buckets with LDS
// staging so the tmp writes go out in coalesced bucket-run bursts (~224 B).
// Fixed-capacity buckets (kCap) + global atomic cursors: no pre-count pass.
// Packed edge: .x = (rowlocal<<19)|col, .y = val bits.
__global__ void bucket_scatter(const int* __restrict__ row, const int* __restrict__ col,
                               const float* __restrict__ val, int* __restrict__ gpos,
                               int2* __restrict__ tmp) {
  __shared__ int hcnt[kNBKT];
  __shared__ int lofs[kNBKT];
  __shared__ int hbase[kNBKT];
  __shared__ int lds[256];
  __shared__ int2 se[kSEPB];
  __shared__ unsigned short sb[kSEPB];
  int t = threadIdx.x;
  long base = (long)blockIdx.x * kSEPB;
  int valid = (int)min((long)kSEPB, (long)kNNZ - base);
  for (int i = t; i < kNBKT; i += 256) hcnt[i] = 0;
  __syncthreads();
  int pk[16], bk[16], rk[16];
  float v[16];
  bool ok[16];
#pragma unroll
  for (int j = 0; j < 16; ++j) {
    long i = base + j * 256 + t;
    ok[j] = (i < kNNZ);
    if (ok[j]) {
      int r = row[i];
      bk[j] = r >> 11;
      pk[j] = ((r & 2047) << 19) | col[i];
      v[j] = val[i];
      rk[j] = atomicAdd(&hcnt[bk[j]], 1);
    }
  }
  __syncthreads();
  // exclusive scan of hcnt -> lofs; reserve global runs -> hbase
  int own = (t < kNBKT) ? hcnt[t] : 0;
  lds[t] = own;
  __syncthreads();
  for (int o = 1; o < 256; o <<= 1) {
    int x = (t >= o) ? lds[t - o] : 0;
    __syncthreads();
    if (t >= o) lds[t] += x;
    __syncthreads();
  }
  if (t < kNBKT) {
    lofs[t] = lds[t] - own;
    hbase[t] = t * kCap + atomicAdd(&gpos[t], own);
  }
  __syncthreads();
  // place into LDS in bucket-sorted order
#pragma unroll
  for (int j = 0; j < 16; ++j) {
    if (ok[j]) {
      int pos = lofs[bk[j]] + rk[j];
      se[pos] = make_int2(pk[j], __float_as_int(v[j]));
      sb[pos] = (unsigned short)bk[j];
    }
  }
  __syncthreads();
  // drain LDS sequentially -> coalesced global runs
#pragma unroll
  for (int j = 0; j < 16; ++j) {
    int pos = t + j * 256;
    if (pos < valid) {
      int b = sb[pos];
      tmp[hbase[b] + (pos - lofs[b])] = se[pos];
    }
  }
}

// Grid = kNBKT*kMC. Per-(bucket,chunk) 2048-row LDS histogram -> ctab.
__global__ void chunk_hist(const int* __restrict__ gpos, const int2* __restrict__ tmp,
                           int* __restrict__ ctab) {
  __shared__ int h[kRowsPerBkt];
  int b = blockIdx.x / kMC, c = blockIdx.x % kMC;
  int t = threadIdx.x;
  for (int i = t; i < kRowsPerBkt; i += 256) h[i] = 0;
  __syncthreads();
  int s = b * kCap + c * kCE;
  int e = b * kCap + gpos[b];
  if (s + kCE < e) e = s + kCE;
  for (int j = s + t; j < e; j += 256) atomicAdd(&h[tmp[j].x >> 19], 1);
  __syncthreads();
  int* dst = ctab + (size_t)blockIdx.x * kRowsPerBkt;
  for (int i = t; i < kRowsPerBkt; i += 256) dst[i] = h[i];
}

// Per-row totals over chunks (ctab -> chunk-exclusive prefixes), block-scan of
// 2048 row totals -> bucket-local rowptr + per-bucket partial.
__global__ void scanA(int* __restrict__ ctab, int* __restrict__ rowptr,
                      int* __restrict__ partials) {
  __shared__ int lsum[256];
  int b = blockIdx.x, t = threadIdx.x;
  int cnt[8];
#pragma unroll
  for (int k = 0; k < 8; ++k) cnt[k] = 0;
  for (int c = 0; c < kMC; ++c) {
    int* p = ctab + (size_t)(b * kMC + c) * kRowsPerBkt;
#pragma unroll
    for (int k = 0; k < 8; ++k) {
      int idx = t * 8 + k;
      int v = p[idx];
      p[idx] = cnt[k];
      cnt[k] += v;
    }
  }
  int s = 0, pref[8];
#pragma unroll
  for (int k = 0; k < 8; ++k) { pref[k] = s; s += cnt[k]; }
  lsum[t] = s;
  __syncthreads();
  for (int o = 1; o < 256; o <<= 1) {
    int v = (t >= o) ? lsum[t - o] : 0;
    __syncthreads();
    if (t >= o) lsum[t] += v;
    __syncthreads();
  }
  int ex = (t == 0) ? 0 : lsum[t - 1];
#pragma unroll
  for (int k = 0; k < 8; ++k) {
    int r = b * kRowsPerBkt + t * 8 + k;
    if (r < kN) rowptr[r] = ex + pref[k];
  }
  if (t == 255) partials[b] = lsum[255];
}

__global__ void scan2(int* __restrict__ partials) {
  __shared__ int lds[256];
  int t = threadIdx.x;
  lds[t] = (t < kNBKT) ? partials[t] : 0;
  __syncthreads();
  for (int o = 1; o < 256; o <<= 1) {
    int v = (t >= o) ? lds[t - o] : 0;
    __syncthreads();
    if (t >= o) lds[t] += v;
    __syncthreads();
  }
  int ex = (t == 0) ? 0 : lds[t - 1];
  if (t < kNBKT) partials[t] = ex;
}

__global__ void scan3(int* __restrict__ rowptr, const int* __restrict__ partials) {
  int i = blockIdx.x * blockDim.x + threadIdx.x;
  if (i < kN) rowptr[i] += partials[i >> 11];
  else if (i == kN) rowptr[kN] = kNNZ;
}

// Grid = kNBKT*kMC. Place edges to final CSR slots; random writes confined to
// the bucket's ~272 KB window.
__global__ void chunk_place(const int* __restrict__ gpos, const int2* __restrict__ tmp,
                            const int* __restrict__ rowptr, const int* __restrict__ ctab,
                            int2* __restrict__ edges) {
  __shared__ int rank[kRowsPerBkt];
  int b = blockIdx.x / kMC, c = blockIdx.x % kMC;
  int t = threadIdx.x;
  for (int i = t; i < kRowsPerBkt; i += 256) rank[i] = 0;
  __syncthreads();
  int s = b * kCap + c * kCE;
  int e = b * kCap + gpos[b];
  if (s + kCE < e) e = s + kCE;
  const int* coff = ctab + (size_t)blockIdx.x * kRowsPerBkt;
  for (int j = s + t; j < e; j += 256) {
    int2 epk = tmp[j];
    int rl = epk.x >> 19;
    int k = atomicAdd(&rank[rl], 1);
    int dst = rowptr[b * kRowsPerBkt + rl] + coff[rl] + k;
    edges[dst] = make_int2(epk.x & 0x7FFFF, epk.y);
  }
}

// Convert concat(uemb, iemb) rows to fp16. One thread per 4 elems.
__global__ void to_half(const float* __restrict__ ue, const float* __restrict__ ie,
                        __half* __restrict__ xh) {
  int t = blockIdx.x * blockDim.x + threadIdx.x;
  if (t >= kN * kD / 4) return;
  int row = t >> 4;
  int g = t & 15;
  const float* src = (row < kUsers) ? (ue + (size_t)row * kD)
                                    : (ie + (size_t)(row - kUsers) * kD);
  float4 v = ((const float4*)src)[g];
  __half2 h01 = __float22half2_rn(make_float2(v.x, v.y));
  __half2 h23 = __float22half2_rn(make_float2(v.z, v.w));
  ((int2*)xh)[t] = make_int2(*(int*)&h01, *(int*)&h23);
}

// One wave per row. 4 edge slots x 16 dim-lanes; fp16 gathers (128 B/row),
// fp32 accumulate via fma_mix; unrolled x4 -> 16 row-gathers in flight.
// Output fp16 only (acc path tolerates the rounding).
__global__ void spmm(const int* __restrict__ rowptr, const int2* __restrict__ edges,
                     const __half* __restrict__ x, __half* __restrict__ yh) {
  int wave = threadIdx.x >> 6;
  int lane = threadIdx.x & 63;
  int eslot = lane >> 4;
  int l16 = lane & 15;
  int r = blockIdx.x * 4 + wave;
  if (r >= kN) return;
  int s = rowptr[r], e = rowptr[r + 1];
  float4 a0 = make_float4(0.f, 0.f, 0.f, 0.f);
  float4 a1 = make_float4(0.f, 0.f, 0.f, 0.f);
  float4 a2 = make_float4(0.f, 0.f, 0.f, 0.f);
  float4 a3 = make_float4(0.f, 0.f, 0.f, 0.f);
  auto fmadd = [&](float4& acc, int2 epk) {
    int2 hv = ((const int2*)(x + (size_t)epk.x * kD))[l16];
    float v = __int_as_float(epk.y);
    __half2 h01 = *(__half2*)&hv.x;
    __half2 h23 = *(__half2*)&hv.y;
    acc.x = fmaf(v, __half2float(__low2half(h01)),  acc.x);
    acc.y = fmaf(v, __half2float(__high2half(h01)), acc.y);
    acc.z = fmaf(v, __half2float(__low2half(h23)),  acc.z);
    acc.w = fmaf(v, __half2float(__high2half(h23)), acc.w);
  };
  int j = s + eslot;
  for (; j + 12 < e; j += 16) {
    int2 e0 = edges[j];
    int2 e1 = edges[j + 4];
    int2 e2 = edges[j + 8];
    int2 e3 = edges[j + 12];
    fmadd(a0, e0); fmadd(a1, e1); fmadd(a2, e2); fmadd(a3, e3);
  }
  for (; j < e; j += 4) fmadd(a0, edges[j]);
  a0.x += a1.x + a2.x + a3.x;
  a0.y += a1.y + a2.y + a3.y;
  a0.z += a1.z + a2.z + a3.z;
  a0.w += a1.w + a2.w + a3.w;
#pragma unroll
  for (int m = 16; m <= 32; m <<= 1) {
    a0.x += __shfl_xor(a0.x, m, 64);
    a0.y += __shfl_xor(a0.y, m, 64);
    a0.z += __shfl_xor(a0.z, m, 64);
    a0.w += __shfl_xor(a0.w, m, 64);
  }
  if (eslot == 0) {
    __half2 h01 = __float22half2_rn(make_float2(a0.x, a0.y));
    __half2 h23 = __float22half2_rn(make_float2(a0.z, a0.w));
    ((int2*)yh)[(size_t)r * 16 + l16] = make_int2(*(int*)&h01, *(int*)&h23);
  }
}

__global__ void acc_init(const int* __restrict__ users, const int* __restrict__ items,
                         const float* __restrict__ uemb, const float* __restrict__ iemb,
                         float* __restrict__ uacc, float* __restrict__ iacc) {
  int tid = blockIdx.x * blockDim.x + threadIdx.x;
  if (tid >= kB * kD) return;
  int b = tid >> 6, d = tid & 63;
  uacc[tid] = uemb[(size_t)users[b] * kD + d];
  iacc[tid] = iemb[(size_t)items[b] * kD + d];
}

// Accumulate the fp16 layer output into the fp32 per-pair accumulators.
__global__ void acc_add(const int* __restrict__ users, const int* __restrict__ items,
                        const __half* __restrict__ xh, float* __restrict__ uacc,
                        float* __restrict__ iacc) {
  int tid = blockIdx.x * blockDim.x + threadIdx.x;
  if (tid >= kB * kD) return;
  int b = tid >> 6, d = tid & 63;
  uacc[tid] += __half2float(xh[(size_t)users[b] * kD + d]);
  iacc[tid] += __half2float(xh[(size_t)(kUsers + items[b]) * kD + d]);
}

// gamma[b] = dot(acc_u, acc_i) / 16
__global__ void finalize(const float* __restrict__ uacc, const float* __restrict__ iacc,
                         float* __restrict__ out) {
  int tid = blockIdx.x * blockDim.x + threadIdx.x;
  if (tid >= kB * kD) return;
  int b = tid >> 6, d = tid & 63;
  float p = uacc[tid] * iacc[tid];
  for (int o = 32; o > 0; o >>= 1) p += __shfl_down(p, o, 64);
  if (d == 0) out[b] = p * 0.0625f;
}

}  // namespace

extern "C" void kernel_launch(void* const* d_in, const int* in_sizes, int n_in,
                              void* d_out, int out_size, void* d_ws, size_t ws_size,
                              hipStream_t stream) {
  const int*   users = (const int*)d_in[0];
  const int*   items = (const int*)d_in[1];
  const int*   erow  = (const int*)d_in[2];
  const int*   ecol  = (const int*)d_in[3];
  const float* evals = (const float*)d_in[4];
  const float* uemb  = (const float*)d_in[5];
  const float* iemb  = (const float*)d_in[6];
  float* out = (float*)d_out;

  char* ws = (char*)d_ws;
  size_t off = 0;
  auto take = [&](size_t bytes) -> char* {
    char* p = ws + off;
    off = (off + bytes + 255) & ~(size_t)255;
    return p;
  };
  int*    rowptr   = (int*)take((size_t)(kN + 1) * 4);
  int*    gpos     = (int*)take((kNBKT + 1) * 4);
  int*    partials = (int*)take(256 * 4);
  int2*   edges    = (int2*)take((size_t)kNNZ * 8);
  int2*   tmp      = (int2*)take((size_t)kNBKT * kCap * 8);  // 48.2 MB
  __half* xh0      = (__half*)take((size_t)kN * kD * 2);     // fp16 ping
  __half* xh1      = (__half*)take((size_t)kN * kD * 2);     // fp16 pong
  float*  uacc     = (float*)take((size_t)kB * kD * 4);
  float*  iacc     = (float*)take((size_t)kB * kD * 4);
  int*    ctab     = (int*)xh0;   // 6.0 MB, dead before to_half writes xh0
  (void)ws_size; (void)in_sizes; (void)n_in; (void)out_size;

  const int nScatBlocks = (kNNZ + kSEPB - 1) / kSEPB;  // 1221

  // --- CSR build: fixed-capacity bucket sort, then parallel counting sort ---
  zero_i32<<<1, 256, 0, stream>>>(gpos, kNBKT);
  bucket_scatter<<<nScatBlocks, 256, 0, stream>>>(erow, ecol, evals, gpos, tmp);
  chunk_hist<<<kNBKT * kMC, 256, 0, stream>>>(gpos, tmp, ctab);
  scanA<<<kNBKT, 256, 0, stream>>>(ctab, rowptr, partials);
  scan2<<<1, 256, 0, stream>>>(partials);
  scan3<<<(kN + 1 + 255) / 256, 256, 0, stream>>>(rowptr, partials);
  chunk_place<<<kNBKT * kMC, 256, 0, stream>>>(gpos, tmp, rowptr, ctab, edges);

  // --- fp16 copy of concat embeddings (after chunk_place: ctab aliases xh0) ---
  to_half<<<(kN * kD / 4 + 255) / 256, 256, 0, stream>>>(uemb, iemb, xh0);
  acc_init<<<(kB * kD) / 256, 256, 0, stream>>>(users, items, uemb, iemb, uacc, iacc);

  // --- 3 propagation layers; fp16 ping-pong ---
  spmm<<<kN / 4, 256, 0, stream>>>(rowptr, edges, xh0, xh1);
  acc_add<<<(kB * kD) / 256, 256, 0, stream>>>(users, items, xh1, uacc, iacc);
  spmm<<<kN / 4, 256, 0, stream>>>(rowptr, edges, xh1, xh0);
  acc_add<<<(kB * kD) / 256, 256, 0, stream>>>(users, items, xh0, uacc, iacc);
  spmm<<<kN / 4, 256, 0, stream>>>(rowptr, edges, xh0, xh1);
  acc_add<<<(kB * kD) / 256, 256, 0, stream>>>(users, items, xh1, uacc, iacc);

  finalize<<<(kB * kD) / 256, 256, 0, stream>>>(uacc, iacc, out);
}

// Round 7
// 663.829 us; speedup vs baseline: 3.0454x; 1.0977x over previous
//
#include <hip/hip_runtime.h>
#include <hip/hip_fp16.h>

namespace {

constexpr int kUsers = 100000;
constexpr int kItems = 200000;
constexpr int kN     = kUsers + kItems;   // 300000
constexpr int kD     = 64;
constexpr int kNNZ   = 5000000;
constexpr int kB     = 16384;
constexpr int kRowsPerBkt = 2048;                       // rows per coarse bucket
constexpr int kNBKT  = (kN + kRowsPerBkt - 1) / kRowsPerBkt;  // 147
constexpr int kSEPB  = 4096;                            // edges per bucket_scatter block
constexpr int kCE    = 8192;                            // edges per finalize chunk
constexpr int kMC    = 5;                               // chunks per bucket
constexpr int kCap   = kMC * kCE;                       // 40960 slots/bucket (mean 34133, sd 185)

__global__ void zero_i32(int* __restrict__ p, int n) {
  int i = blockIdx.x * blockDim.x + threadIdx.x;
  if (i < n) p[i] = 0;
}

// Counting-sort partition of 4096 edges into 147 coarse buckets with LDS
// staging so the tmp writes go out in coalesced bucket-run bursts (~224 B).
// Fixed-capacity buckets (kCap) + global atomic cursors: no pre-count pass.
// Packed edge: .x = (rowlocal<<19)|col, .y = val bits.
__global__ void bucket_scatter(const int* __restrict__ row, const int* __restrict__ col,
                               const float* __restrict__ val, int* __restrict__ gpos,
                               int2* __restrict__ tmp) {
  __shared__ int hcnt[kNBKT];
  __shared__ int lofs[kNBKT];
  __shared__ int hbase[kNBKT];
  __shared__ int lds[256];
  __shared__ int2 se[kSEPB];
  __shared__ unsigned short sb[kSEPB];
  int t = threadIdx.x;
  long base = (long)blockIdx.x * kSEPB;
  int valid = (int)min((long)kSEPB, (long)kNNZ - base);
  for (int i = t; i < kNBKT; i += 256) hcnt[i] = 0;
  __syncthreads();
  int pk[16], bk[16], rk[16];
  float v[16];
  bool ok[16];
#pragma unroll
  for (int j = 0; j < 16; ++j) {
    long i = base + j * 256 + t;
    ok[j] = (i < kNNZ);
    if (ok[j]) {
      int r = row[i];
      bk[j] = r >> 11;
      pk[j] = ((r & 2047) << 19) | col[i];
      v[j] = val[i];
      rk[j] = atomicAdd(&hcnt[bk[j]], 1);
    }
  }
  __syncthreads();
  // exclusive scan of hcnt -> lofs; reserve global runs -> hbase
  int own = (t < kNBKT) ? hcnt[t] : 0;
  lds[t] = own;
  __syncthreads();
  for (int o = 1; o < 256; o <<= 1) {
    int x = (t >= o) ? lds[t - o] : 0;
    __syncthreads();
    if (t >= o) lds[t] += x;
    __syncthreads();
  }
  if (t < kNBKT) {
    lofs[t] = lds[t] - own;
    hbase[t] = t * kCap + atomicAdd(&gpos[t], own);
  }
  __syncthreads();
  // place into LDS in bucket-sorted order
#pragma unroll
  for (int j = 0; j < 16; ++j) {
    if (ok[j]) {
      int pos = lofs[bk[j]] + rk[j];
      se[pos] = make_int2(pk[j], __float_as_int(v[j]));
      sb[pos] = (unsigned short)bk[j];
    }
  }
  __syncthreads();
  // drain LDS sequentially -> coalesced global runs
#pragma unroll
  for (int j = 0; j < 16; ++j) {
    int pos = t + j * 256;
    if (pos < valid) {
      int b = sb[pos];
      tmp[hbase[b] + (pos - lofs[b])] = se[pos];
    }
  }
}

// Grid = kNBKT*kMC. Per-(bucket,chunk) 2048-row LDS histogram -> ctab.
__global__ void chunk_hist(const int* __restrict__ gpos, const int2* __restrict__ tmp,
                           int* __restrict__ ctab) {
  __shared__ int h[kRowsPerBkt];
  int b = blockIdx.x / kMC, c = blockIdx.x % kMC;
  int t = threadIdx.x;
  for (int i = t; i < kRowsPerBkt; i += 256) h[i] = 0;
  __syncthreads();
  int s = b * kCap + c * kCE;
  int e = b * kCap + gpos[b];
  if (s + kCE < e) e = s + kCE;
  for (int j = s + t; j < e; j += 256) atomicAdd(&h[tmp[j].x >> 19], 1);
  __syncthreads();
  int* dst = ctab + (size_t)blockIdx.x * kRowsPerBkt;
  for (int i = t; i < kRowsPerBkt; i += 256) dst[i] = h[i];
}

// Per-row totals over chunks (ctab -> chunk-exclusive prefixes), block-scan of
// 2048 row totals -> bucket-local rowptr + per-bucket partial.
__global__ void scanA(int* __restrict__ ctab, int* __restrict__ rowptr,
                      int* __restrict__ partials) {
  __shared__ int lsum[256];
  int b = blockIdx.x, t = threadIdx.x;
  int cnt[8];
#pragma unroll
  for (int k = 0; k < 8; ++k) cnt[k] = 0;
  for (int c = 0; c < kMC; ++c) {
    int* p = ctab + (size_t)(b * kMC + c) * kRowsPerBkt;
#pragma unroll
    for (int k = 0; k < 8; ++k) {
      int idx = t * 8 + k;
      int v = p[idx];
      p[idx] = cnt[k];
      cnt[k] += v;
    }
  }
  int s = 0, pref[8];
#pragma unroll
  for (int k = 0; k < 8; ++k) { pref[k] = s; s += cnt[k]; }
  lsum[t] = s;
  __syncthreads();
  for (int o = 1; o < 256; o <<= 1) {
    int v = (t >= o) ? lsum[t - o] : 0;
    __syncthreads();
    if (t >= o) lsum[t] += v;
    __syncthreads();
  }
  int ex = (t == 0) ? 0 : lsum[t - 1];
#pragma unroll
  for (int k = 0; k < 8; ++k) {
    int r = b * kRowsPerBkt + t * 8 + k;
    if (r < kN) rowptr[r] = ex + pref[k];
  }
  if (t == 255) partials[b] = lsum[255];
}

__global__ void scan2(int* __restrict__ partials) {
  __shared__ int lds[256];
  int t = threadIdx.x;
  lds[t] = (t < kNBKT) ? partials[t] : 0;
  __syncthreads();
  for (int o = 1; o < 256; o <<= 1) {
    int v = (t >= o) ? lds[t - o] : 0;
    __syncthreads();
    if (t >= o) lds[t] += v;
    __syncthreads();
  }
  int ex = (t == 0) ? 0 : lds[t - 1];
  if (t < kNBKT) partials[t] = ex;
}

__global__ void scan3(int* __restrict__ rowptr, const int* __restrict__ partials) {
  int i = blockIdx.x * blockDim.x + threadIdx.x;
  if (i < kN) rowptr[i] += partials[i >> 11];
  else if (i == kN) rowptr[kN] = kNNZ;
}

// Grid = kNBKT*kMC. Place edges to final CSR slots; random writes confined to
// the bucket's ~272 KB window.
__global__ void chunk_place(const int* __restrict__ gpos, const int2* __restrict__ tmp,
                            const int* __restrict__ rowptr, const int* __restrict__ ctab,
                            int2* __restrict__ edges) {
  __shared__ int rank[kRowsPerBkt];
  int b = blockIdx.x / kMC, c = blockIdx.x % kMC;
  int t = threadIdx.x;
  for (int i = t; i < kRowsPerBkt; i += 256) rank[i] = 0;
  __syncthreads();
  int s = b * kCap + c * kCE;
  int e = b * kCap + gpos[b];
  if (s + kCE < e) e = s + kCE;
  const int* coff = ctab + (size_t)blockIdx.x * kRowsPerBkt;
  for (int j = s + t; j < e; j += 256) {
    int2 epk = tmp[j];
    int rl = epk.x >> 19;
    int k = atomicAdd(&rank[rl], 1);
    int dst = rowptr[b * kRowsPerBkt + rl] + coff[rl] + k;
    edges[dst] = make_int2(epk.x & 0x7FFFF, epk.y);
  }
}

// Convert concat(uemb, iemb) rows to fp16. One thread per 4 elems.
__global__ void to_half(const float* __restrict__ ue, const float* __restrict__ ie,
                        __half* __restrict__ xh) {
  int t = blockIdx.x * blockDim.x + threadIdx.x;
  if (t >= kN * kD / 4) return;
  int row = t >> 4;
  int g = t & 15;
  const float* src = (row < kUsers) ? (ue + (size_t)row * kD)
                                    : (ie + (size_t)(row - kUsers) * kD);
  float4 v = ((const float4*)src)[g];
  __half2 h01 = __float22half2_rn(make_float2(v.x, v.y));
  __half2 h23 = __float22half2_rn(make_float2(v.z, v.w));
  ((int2*)xh)[t] = make_int2(*(int*)&h01, *(int*)&h23);
}

// One wave per row. 8 edge slots x 8 dim-lanes; each lane gathers 16 B
// (dwordx4 = 8 fp16 dims) -> one gather instruction covers 8 edges x 128 B.
// fp32 accumulate via fma_mix; unroll x2 -> 16 row-gathers in flight.
__global__ void spmm(const int* __restrict__ rowptr, const int2* __restrict__ edges,
                     const __half* __restrict__ x, __half* __restrict__ yh) {
  int wave = threadIdx.x >> 6;
  int lane = threadIdx.x & 63;
  int eslot = lane >> 3;         // 8 edge slots
  int l8 = lane & 7;             // dims l8*8 .. l8*8+7
  int r = blockIdx.x * 4 + wave;
  if (r >= kN) return;
  int s = rowptr[r], e = rowptr[r + 1];
  float a0[8], a1[8];
#pragma unroll
  for (int k = 0; k < 8; ++k) { a0[k] = 0.f; a1[k] = 0.f; }
  auto fmadd = [&](float* acc, int2 epk) {
    int4 hv = ((const int4*)(x + (size_t)epk.x * kD))[l8];
    float v = __int_as_float(epk.y);
    const __half2* h = (const __half2*)&hv;
#pragma unroll
    for (int k = 0; k < 4; ++k) {
      acc[2 * k]     = fmaf(v, __half2float(__low2half(h[k])),  acc[2 * k]);
      acc[2 * k + 1] = fmaf(v, __half2float(__high2half(h[k])), acc[2 * k + 1]);
    }
  };
  int j = s + eslot;
  for (; j + 8 < e; j += 16) {
    int2 e0 = edges[j];
    int2 e1 = edges[j + 8];
    fmadd(a0, e0);
    fmadd(a1, e1);
  }
  if (j < e) fmadd(a0, edges[j]);
#pragma unroll
  for (int k = 0; k < 8; ++k) a0[k] += a1[k];
#pragma unroll
  for (int m = 8; m <= 32; m <<= 1) {
#pragma unroll
    for (int k = 0; k < 8; ++k) a0[k] += __shfl_xor(a0[k], m, 64);
  }
  if (eslot == 0) {
    int4 pk;
    __half2* ph = (__half2*)&pk;
#pragma unroll
    for (int k = 0; k < 4; ++k)
      ph[k] = __float22half2_rn(make_float2(a0[2 * k], a0[2 * k + 1]));
    ((int4*)yh)[(size_t)r * 8 + l8] = pk;
  }
}

__global__ void acc_init(const int* __restrict__ users, const int* __restrict__ items,
                         const float* __restrict__ uemb, const float* __restrict__ iemb,
                         float* __restrict__ uacc, float* __restrict__ iacc) {
  int tid = blockIdx.x * blockDim.x + threadIdx.x;
  if (tid >= kB * kD) return;
  int b = tid >> 6, d = tid & 63;
  uacc[tid] = uemb[(size_t)users[b] * kD + d];
  iacc[tid] = iemb[(size_t)items[b] * kD + d];
}

// Accumulate the fp16 layer output into the fp32 per-pair accumulators.
__global__ void acc_add(const int* __restrict__ users, const int* __restrict__ items,
                        const __half* __restrict__ xh, float* __restrict__ uacc,
                        float* __restrict__ iacc) {
  int tid = blockIdx.x * blockDim.x + threadIdx.x;
  if (tid >= kB * kD) return;
  int b = tid >> 6, d = tid & 63;
  uacc[tid] += __half2float(xh[(size_t)users[b] * kD + d]);
  iacc[tid] += __half2float(xh[(size_t)(kUsers + items[b]) * kD + d]);
}

// gamma[b] = dot(acc_u, acc_i) / 16
__global__ void finalize(const float* __restrict__ uacc, const float* __restrict__ iacc,
                         float* __restrict__ out) {
  int tid = blockIdx.x * blockDim.x + threadIdx.x;
  if (tid >= kB * kD) return;
  int b = tid >> 6, d = tid & 63;
  float p = uacc[tid] * iacc[tid];
  for (int o = 32; o > 0; o >>= 1) p += __shfl_down(p, o, 64);
  if (d == 0) out[b] = p * 0.0625f;
}

}  // namespace

extern "C" void kernel_launch(void* const* d_in, const int* in_sizes, int n_in,
                              void* d_out, int out_size, void* d_ws, size_t ws_size,
                              hipStream_t stream) {
  const int*   users = (const int*)d_in[0];
  const int*   items = (const int*)d_in[1];
  const int*   erow  = (const int*)d_in[2];
  const int*   ecol  = (const int*)d_in[3];
  const float* evals = (const float*)d_in[4];
  const float* uemb  = (const float*)d_in[5];
  const float* iemb  = (const float*)d_in[6];
  float* out = (float*)d_out;

  char* ws = (char*)d_ws;
  size_t off = 0;
  auto take = [&](size_t bytes) -> char* {
    char* p = ws + off;
    off = (off + bytes + 255) & ~(size_t)255;
    return p;
  };
  int*    rowptr   = (int*)take((size_t)(kN + 1) * 4);
  int*    gpos     = (int*)take((kNBKT + 1) * 4);
  int*    partials = (int*)take(256 * 4);
  int2*   edges    = (int2*)take((size_t)kNNZ * 8);
  int2*   tmp      = (int2*)take((size_t)kNBKT * kCap * 8);  // 48.2 MB
  __half* xh0      = (__half*)take((size_t)kN * kD * 2);     // fp16 ping
  __half* xh1      = (__half*)take((size_t)kN * kD * 2);     // fp16 pong
  float*  uacc     = (float*)take((size_t)kB * kD * 4);
  float*  iacc     = (float*)take((size_t)kB * kD * 4);
  int*    ctab     = (int*)xh0;   // 6.0 MB, dead before to_half writes xh0
  (void)ws_size; (void)in_sizes; (void)n_in; (void)out_size;

  const int nScatBlocks = (kNNZ + kSEPB - 1) / kSEPB;  // 1221

  // --- CSR build: fixed-capacity bucket sort, then parallel counting sort ---
  zero_i32<<<1, 256, 0, stream>>>(gpos, kNBKT);
  bucket_scatter<<<nScatBlocks, 256, 0, stream>>>(erow, ecol, evals, gpos, tmp);
  chunk_hist<<<kNBKT * kMC, 256, 0, stream>>>(gpos, tmp, ctab);
  scanA<<<kNBKT, 256, 0, stream>>>(ctab, rowptr, partials);
  scan2<<<1, 256, 0, stream>>>(partials);
  scan3<<<(kN + 1 + 255) / 256, 256, 0, stream>>>(rowptr, partials);
  chunk_place<<<kNBKT * kMC, 256, 0, stream>>>(gpos, tmp, rowptr, ctab, edges);

  // --- fp16 copy of concat embeddings (after chunk_place: ctab aliases xh0) ---
  to_half<<<(kN * kD / 4 + 255) / 256, 256, 0, stream>>>(uemb, iemb, xh0);
  acc_init<<<(kB * kD) / 256, 256, 0, stream>>>(users, items, uemb, iemb, uacc, iacc);

  // --- 3 propagation layers; fp16 ping-pong ---
  spmm<<<kN / 4, 256, 0, stream>>>(rowptr, edges, xh0, xh1);
  acc_add<<<(kB * kD) / 256, 256, 0, stream>>>(users, items, xh1, uacc, iacc);
  spmm<<<kN / 4, 256, 0, stream>>>(rowptr, edges, xh1, xh0);
  acc_add<<<(kB * kD) / 256, 256, 0, stream>>>(users, items, xh0, uacc, iacc);
  spmm<<<kN / 4, 256, 0, stream>>>(rowptr, edges, xh0, xh1);
  acc_add<<<(kB * kD) / 256, 256, 0, stream>>>(users, items, xh1, uacc, iacc);

  finalize<<<(kB * kD) / 256, 256, 0, stream>>>(uacc, iacc, out);
}

// Round 8
// 629.117 us; speedup vs baseline: 3.2134x; 1.0552x over previous
//
#include <hip/hip_runtime.h>
#include <hip/hip_fp16.h>

namespace {

constexpr int kUsers = 100000;
constexpr int kItems = 200000;
constexpr int kN     = kUsers + kItems;   // 300000
constexpr int kD     = 64;
constexpr int kNNZ   = 5000000;
constexpr int kB     = 16384;
constexpr int kRowsPerBkt = 2048;                       // rows per coarse bucket
constexpr int kNBKT  = (kN + kRowsPerBkt - 1) / kRowsPerBkt;  // 147
constexpr int kSEPB  = 4096;                            // edges per bucket_scatter block
constexpr int kCE    = 8192;                            // edges per finalize chunk
constexpr int kMC    = 5;                               // chunks per bucket
constexpr int kCap   = kMC * kCE;                       // 40960 slots/bucket (mean 34133, sd 185)

__global__ void zero_i32(int* __restrict__ p, int n) {
  int i = blockIdx.x * blockDim.x + threadIdx.x;
  if (i < n) p[i] = 0;
}

// Counting-sort partition of 4096 edges into 147 coarse buckets; per-wave LDS
// histograms (4x147) cut same-address atomic serialization 4x. LDS staging so
// tmp writes go out in coalesced bucket-run bursts.
// Packed edge: .x = (rowlocal<<19)|col, .y = val bits.
__global__ void bucket_scatter(const int* __restrict__ row, const int* __restrict__ col,
                               const float* __restrict__ val, int* __restrict__ gpos,
                               int2* __restrict__ tmp) {
  __shared__ int hcnt[4][kNBKT];   // per-wave counts -> wave-exclusive offsets
  __shared__ int lofs[kNBKT];
  __shared__ int hbase[kNBKT];
  __shared__ int lds[256];
  __shared__ int2 se[kSEPB];
  __shared__ unsigned short sb[kSEPB];
  int t = threadIdx.x;
  int wv = t >> 6;
  long base = (long)blockIdx.x * kSEPB;
  int valid = (int)min((long)kSEPB, (long)kNNZ - base);
  for (int i = t; i < kNBKT; i += 256) {
    hcnt[0][i] = 0; hcnt[1][i] = 0; hcnt[2][i] = 0; hcnt[3][i] = 0;
  }
  __syncthreads();
  int pk[16], bk[16], rk[16];
  float v[16];
  bool ok[16];
#pragma unroll
  for (int j = 0; j < 16; ++j) {
    long i = base + j * 256 + t;
    ok[j] = (i < kNNZ);
    if (ok[j]) {
      int r = row[i];
      bk[j] = r >> 11;
      pk[j] = ((r & 2047) << 19) | col[i];
      v[j] = val[i];
      rk[j] = atomicAdd(&hcnt[wv][bk[j]], 1);
    }
  }
  __syncthreads();
  // per-bucket: wave-exclusive offsets + total; then block scan of totals
  int own = 0;
  if (t < kNBKT) {
    int c0 = hcnt[0][t], c1 = hcnt[1][t], c2 = hcnt[2][t], c3 = hcnt[3][t];
    hcnt[0][t] = 0; hcnt[1][t] = c0; hcnt[2][t] = c0 + c1; hcnt[3][t] = c0 + c1 + c2;
    own = c0 + c1 + c2 + c3;
  }
  lds[t] = own;
  __syncthreads();
  for (int o = 1; o < 256; o <<= 1) {
    int x = (t >= o) ? lds[t - o] : 0;
    __syncthreads();
    if (t >= o) lds[t] += x;
    __syncthreads();
  }
  if (t < kNBKT) {
    lofs[t] = lds[t] - own;
    hbase[t] = t * kCap + atomicAdd(&gpos[t], own);
  }
  __syncthreads();
  // place into LDS in bucket-sorted order
#pragma unroll
  for (int j = 0; j < 16; ++j) {
    if (ok[j]) {
      int pos = lofs[bk[j]] + hcnt[wv][bk[j]] + rk[j];
      se[pos] = make_int2(pk[j], __float_as_int(v[j]));
      sb[pos] = (unsigned short)bk[j];
    }
  }
  __syncthreads();
  // drain LDS sequentially -> coalesced global runs
#pragma unroll
  for (int j = 0; j < 16; ++j) {
    int pos = t + j * 256;
    if (pos < valid) {
      int b = sb[pos];
      tmp[hbase[b] + (pos - lofs[b])] = se[pos];
    }
  }
}

// Grid = kNBKT*kMC. Per-(bucket,chunk) 2048-row LDS histogram -> ctab.
__global__ void chunk_hist(const int* __restrict__ gpos, const int2* __restrict__ tmp,
                           int* __restrict__ ctab) {
  __shared__ int h[kRowsPerBkt];
  int b = blockIdx.x / kMC, c = blockIdx.x % kMC;
  int t = threadIdx.x;
  for (int i = t; i < kRowsPerBkt; i += 256) h[i] = 0;
  __syncthreads();
  int s = b * kCap + c * kCE;
  int e = b * kCap + gpos[b];
  if (s + kCE < e) e = s + kCE;
  for (int j = s + t; j < e; j += 256) atomicAdd(&h[tmp[j].x >> 19], 1);
  __syncthreads();
  int* dst = ctab + (size_t)blockIdx.x * kRowsPerBkt;
  for (int i = t; i < kRowsPerBkt; i += 256) dst[i] = h[i];
}

// Per-row totals over chunks (ctab -> chunk-exclusive prefixes), block-scan of
// 2048 row totals -> bucket-local rowptr + per-bucket partial.
__global__ void scanA(int* __restrict__ ctab, int* __restrict__ rowptr,
                      int* __restrict__ partials) {
  __shared__ int lsum[256];
  int b = blockIdx.x, t = threadIdx.x;
  int cnt[8];
#pragma unroll
  for (int k = 0; k < 8; ++k) cnt[k] = 0;
  for (int c = 0; c < kMC; ++c) {
    int* p = ctab + (size_t)(b * kMC + c) * kRowsPerBkt;
#pragma unroll
    for (int k = 0; k < 8; ++k) {
      int idx = t * 8 + k;
      int v = p[idx];
      p[idx] = cnt[k];
      cnt[k] += v;
    }
  }
  int s = 0, pref[8];
#pragma unroll
  for (int k = 0; k < 8; ++k) { pref[k] = s; s += cnt[k]; }
  lsum[t] = s;
  __syncthreads();
  for (int o = 1; o < 256; o <<= 1) {
    int v = (t >= o) ? lsum[t - o] : 0;
    __syncthreads();
    if (t >= o) lsum[t] += v;
    __syncthreads();
  }
  int ex = (t == 0) ? 0 : lsum[t - 1];
#pragma unroll
  for (int k = 0; k < 8; ++k) {
    int r = b * kRowsPerBkt + t * 8 + k;
    if (r < kN) rowptr[r] = ex + pref[k];
  }
  if (t == 255) partials[b] = lsum[255];
}

__global__ void scan2(int* __restrict__ partials) {
  __shared__ int lds[256];
  int t = threadIdx.x;
  lds[t] = (t < kNBKT) ? partials[t] : 0;
  __syncthreads();
  for (int o = 1; o < 256; o <<= 1) {
    int v = (t >= o) ? lds[t - o] : 0;
    __syncthreads();
    if (t >= o) lds[t] += v;
    __syncthreads();
  }
  int ex = (t == 0) ? 0 : lds[t - 1];
  if (t < kNBKT) partials[t] = ex;
}

__global__ void scan3(int* __restrict__ rowptr, const int* __restrict__ partials) {
  int i = blockIdx.x * blockDim.x + threadIdx.x;
  if (i < kN) rowptr[i] += partials[i >> 11];
  else if (i == kN) rowptr[kN] = kNNZ;
}

// Grid = kNBKT*kMC. Place edges to final CSR slots; random writes confined to
// the bucket's ~272 KB window.
__global__ void chunk_place(const int* __restrict__ gpos, const int2* __restrict__ tmp,
                            const int* __restrict__ rowptr, const int* __restrict__ ctab,
                            int2* __restrict__ edges) {
  __shared__ int rank[kRowsPerBkt];
  int b = blockIdx.x / kMC, c = blockIdx.x % kMC;
  int t = threadIdx.x;
  for (int i = t; i < kRowsPerBkt; i += 256) rank[i] = 0;
  __syncthreads();
  int s = b * kCap + c * kCE;
  int e = b * kCap + gpos[b];
  if (s + kCE < e) e = s + kCE;
  const int* coff = ctab + (size_t)blockIdx.x * kRowsPerBkt;
  for (int j = s + t; j < e; j += 256) {
    int2 epk = tmp[j];
    int rl = epk.x >> 19;
    int k = atomicAdd(&rank[rl], 1);
    int dst = rowptr[b * kRowsPerBkt + rl] + coff[rl] + k;
    edges[dst] = make_int2(epk.x & 0x7FFFF, epk.y);
  }
}

// Convert concat(uemb, iemb) rows to fp16. One thread per 4 elems.
__global__ void to_half(const float* __restrict__ ue, const float* __restrict__ ie,
                        __half* __restrict__ xh) {
  int t = blockIdx.x * blockDim.x + threadIdx.x;
  if (t >= kN * kD / 4) return;
  int row = t >> 4;
  int g = t & 15;
  const float* src = (row < kUsers) ? (ue + (size_t)row * kD)
                                    : (ie + (size_t)(row - kUsers) * kD);
  float4 v = ((const float4*)src)[g];
  __half2 h01 = __float22half2_rn(make_float2(v.x, v.y));
  __half2 h23 = __float22half2_rn(make_float2(v.z, v.w));
  ((int2*)xh)[t] = make_int2(*(int*)&h01, *(int*)&h23);
}

// Reduction-free spmm: one 8-lane group per row (8 rows/wave). Lane l owns
// dims [8l, 8l+8) -> gathers its own int4 (16 B), accumulates the full row in
// registers, coalesced 128 B store. Loop to wave-max degree with clamped
// addresses + zeroed weights for finished groups (dead gathers are L1 hits).
__global__ void spmm(const int* __restrict__ rowptr, const int2* __restrict__ edges,
                     const __half* __restrict__ x, __half* __restrict__ yh) {
  int t = threadIdx.x;
  int l = t & 7;                               // dim octet
  int wid = (blockIdx.x * 256 + t) >> 6;       // global wave id
  int g = (t >> 3) & 7;                        // group (row) within wave
  int r = wid * 8 + g;
  int s = 0, e = 0;
  if (r < kN) { s = rowptr[r]; e = rowptr[r + 1]; }
  int mx = e - s;
#pragma unroll
  for (int m = 8; m <= 32; m <<= 1) mx = max(mx, __shfl_xor(mx, m, 64));
  float acc[8];
#pragma unroll
  for (int k = 0; k < 8; ++k) acc[k] = 0.f;
  int last = max(e - 1, 0);
  int j = s;
  for (int it = 0; it < mx; it += 2) {
    int j0 = min(j, last);
    int j1 = min(j + 1, last);
    int2 e0 = edges[j0];
    int2 e1 = edges[j1];
    float v0 = (j < e) ? __int_as_float(e0.y) : 0.f;
    float v1 = (j + 1 < e) ? __int_as_float(e1.y) : 0.f;
    int4 h0 = ((const int4*)(x + (size_t)e0.x * kD))[l];
    int4 h1 = ((const int4*)(x + (size_t)e1.x * kD))[l];
    const __half2* p0 = (const __half2*)&h0;
    const __half2* p1 = (const __half2*)&h1;
#pragma unroll
    for (int k = 0; k < 4; ++k) {
      acc[2 * k]     = fmaf(v0, __half2float(__low2half(p0[k])),  acc[2 * k]);
      acc[2 * k + 1] = fmaf(v0, __half2float(__high2half(p0[k])), acc[2 * k + 1]);
    }
#pragma unroll
    for (int k = 0; k < 4; ++k) {
      acc[2 * k]     = fmaf(v1, __half2float(__low2half(p1[k])),  acc[2 * k]);
      acc[2 * k + 1] = fmaf(v1, __half2float(__high2half(p1[k])), acc[2 * k + 1]);
    }
    j += 2;
  }
  if (r < kN) {
    int4 pk;
    __half2* ph = (__half2*)&pk;
#pragma unroll
    for (int k = 0; k < 4; ++k)
      ph[k] = __float22half2_rn(make_float2(acc[2 * k], acc[2 * k + 1]));
    ((int4*)yh)[(size_t)r * 8 + l] = pk;
  }
}

__global__ void acc_init(const int* __restrict__ users, const int* __restrict__ items,
                         const float* __restrict__ uemb, const float* __restrict__ iemb,
                         float* __restrict__ uacc, float* __restrict__ iacc) {
  int tid = blockIdx.x * blockDim.x + threadIdx.x;
  if (tid >= kB * kD) return;
  int b = tid >> 6, d = tid & 63;
  uacc[tid] = uemb[(size_t)users[b] * kD + d];
  iacc[tid] = iemb[(size_t)items[b] * kD + d];
}

// Accumulate the fp16 layer output into the fp32 per-pair accumulators.
__global__ void acc_add(const int* __restrict__ users, const int* __restrict__ items,
                        const __half* __restrict__ xh, float* __restrict__ uacc,
                        float* __restrict__ iacc) {
  int tid = blockIdx.x * blockDim.x + threadIdx.x;
  if (tid >= kB * kD) return;
  int b = tid >> 6, d = tid & 63;
  uacc[tid] += __half2float(xh[(size_t)users[b] * kD + d]);
  iacc[tid] += __half2float(xh[(size_t)(kUsers + items[b]) * kD + d]);
}

// gamma[b] = dot(acc_u, acc_i) / 16
__global__ void finalize(const float* __restrict__ uacc, const float* __restrict__ iacc,
                         float* __restrict__ out) {
  int tid = blockIdx.x * blockDim.x + threadIdx.x;
  if (tid >= kB * kD) return;
  int b = tid >> 6, d = tid & 63;
  float p = uacc[tid] * iacc[tid];
  for (int o = 32; o > 0; o >>= 1) p += __shfl_down(p, o, 64);
  if (d == 0) out[b] = p * 0.0625f;
}

}  // namespace

extern "C" void kernel_launch(void* const* d_in, const int* in_sizes, int n_in,
                              void* d_out, int out_size, void* d_ws, size_t ws_size,
                              hipStream_t stream) {
  const int*   users = (const int*)d_in[0];
  const int*   items = (const int*)d_in[1];
  const int*   erow  = (const int*)d_in[2];
  const int*   ecol  = (const int*)d_in[3];
  const float* evals = (const float*)d_in[4];
  const float* uemb  = (const float*)d_in[5];
  const float* iemb  = (const float*)d_in[6];
  float* out = (float*)d_out;

  char* ws = (char*)d_ws;
  size_t off = 0;
  auto take = [&](size_t bytes) -> char* {
    char* p = ws + off;
    off = (off + bytes + 255) & ~(size_t)255;
    return p;
  };
  int*    rowptr   = (int*)take((size_t)(kN + 1) * 4);
  int*    gpos     = (int*)take((kNBKT + 1) * 4);
  int*    partials = (int*)take(256 * 4);
  int2*   edges    = (int2*)take((size_t)kNNZ * 8);
  int2*   tmp      = (int2*)take((size_t)kNBKT * kCap * 8);  // 48.2 MB
  __half* xh0      = (__half*)take((size_t)kN * kD * 2);     // fp16 ping
  __half* xh1      = (__half*)take((size_t)kN * kD * 2);     // fp16 pong
  float*  uacc     = (float*)take((size_t)kB * kD * 4);
  float*  iacc     = (float*)take((size_t)kB * kD * 4);
  int*    ctab     = (int*)xh0;   // 6.0 MB, dead before to_half writes xh0
  (void)ws_size; (void)in_sizes; (void)n_in; (void)out_size;

  const int nScatBlocks = (kNNZ + kSEPB - 1) / kSEPB;  // 1221
  const int nSpmmBlocks = (kN + 31) / 32;              // 8 rows/wave, 4 waves/block

  // --- CSR build: fixed-capacity bucket sort, then parallel counting sort ---
  zero_i32<<<1, 256, 0, stream>>>(gpos, kNBKT);
  bucket_scatter<<<nScatBlocks, 256, 0, stream>>>(erow, ecol, evals, gpos, tmp);
  chunk_hist<<<kNBKT * kMC, 256, 0, stream>>>(gpos, tmp, ctab);
  scanA<<<kNBKT, 256, 0, stream>>>(ctab, rowptr, partials);
  scan2<<<1, 256, 0, stream>>>(partials);
  scan3<<<(kN + 1 + 255) / 256, 256, 0, stream>>>(rowptr, partials);
  chunk_place<<<kNBKT * kMC, 256, 0, stream>>>(gpos, tmp, rowptr, ctab, edges);

  // --- fp16 copy of concat embeddings (after chunk_place: ctab aliases xh0) ---
  to_half<<<(kN * kD / 4 + 255) / 256, 256, 0, stream>>>(uemb, iemb, xh0);
  acc_init<<<(kB * kD) / 256, 256, 0, stream>>>(users, items, uemb, iemb, uacc, iacc);

  // --- 3 propagation layers; fp16 ping-pong ---
  spmm<<<nSpmmBlocks, 256, 0, stream>>>(rowptr, edges, xh0, xh1);
  acc_add<<<(kB * kD) / 256, 256, 0, stream>>>(users, items, xh1, uacc, iacc);
  spmm<<<nSpmmBlocks, 256, 0, stream>>>(rowptr, edges, xh1, xh0);
  acc_add<<<(kB * kD) / 256, 256, 0, stream>>>(users, items, xh0, uacc, iacc);
  spmm<<<nSpmmBlocks, 256, 0, stream>>>(rowptr, edges, xh0, xh1);
  acc_add<<<(kB * kD) / 256, 256, 0, stream>>>(users, items, xh1, uacc, iacc);

  finalize<<<(kB * kD) / 256, 256, 0, stream>>>(uacc, iacc, out);
}